// Round 16
// baseline (488.473 us; speedup 1.0000x reference)
//
#include <hip/hip_runtime.h>
#include <hip/hip_bf16.h>
#include <math.h>

// Flow log_prob. R16: L6 expm switched from fused chain to per-term kernels
// (template taylor_term<S>, grid (S/64, nvec)). R10/R11/R15 evidence: hipcc
// spills any >=96-VGPR register-resident M-row array in barrier-loop chain
// kernels (R15: VGPR=84 < 96 needed, WRITE_SIZE 16MB of scratch stores).
// L7's per-term streaming structure never spilled -> reuse it for L6.

#define NXEL 1572864  // 8*256*256*3

typedef __attribute__((ext_vector_type(8))) short bf16x8;
typedef __attribute__((ext_vector_type(4))) float f32x4;

__device__ inline unsigned pkbf(float a, float b) {
  union { __hip_bfloat16 h; unsigned short u; } ca, cb2;
  ca.h = __float2bfloat16(a);
  cb2.h = __float2bfloat16(b);
  return (unsigned)ca.u | ((unsigned)cb2.u << 16);
}

// ---------- one-shot prep ----------
__global__ __launch_bounds__(256) void prep_all_kernel(
    const float* __restrict__ M1, const float* __restrict__ M2,
    const float* __restrict__ M3, const float* __restrict__ M4,
    const float* __restrict__ M5, const float* __restrict__ M6,
    const float* __restrict__ M7, const float* __restrict__ cw1,
    const float* __restrict__ cw2, const float* __restrict__ dw1,
    const float* __restrict__ dw2, float* __restrict__ MT,
    __hip_bfloat16* __restrict__ MTB, float* __restrict__ TR,
    __hip_bfloat16* __restrict__ CWT1, __hip_bfloat16* __restrict__ CWT2,
    __hip_bfloat16* __restrict__ DWT1, __hip_bfloat16* __restrict__ DWT2) {
  int bid = blockIdx.x, tid = threadIdx.x;
  if (bid < 48) {
    int idx = bid * 256 + tid;
    if (idx < 12240) {
      const int cum[5] = {0, 144, 720, 3024, 12240};
      int l = 0;
      while (idx >= cum[l + 1]) l++;
      int local = idx - cum[l];
      int s = 12 << l;
      int k = local / s, c = local - k * s;
      const float* Mp = l == 0 ? M1 : l == 1 ? M2 : l == 2 ? M3 : M4;
      MT[idx] = -Mp[c * s + k];
    }
  } else if (bid < 3072) {
    int idx = (bid - 48) * 256 + tid;
    if (idx < 774144) {
      const int cum[4] = {0, 36864, 184320, 774144};
      int l = 0;
      while (idx >= cum[l + 1]) l++;
      const float* Mp = l == 0 ? M5 : l == 1 ? M6 : M7;
      MTB[idx] = __float2bfloat16(-Mp[idx - cum[l]]);
    }
  } else if (bid < 3079) {
    __shared__ float red[256];
    int l = bid - 3072;
    const float* Mp = l == 0 ? M1 : l == 1 ? M2 : l == 2 ? M3 : l == 3 ? M4
                    : l == 4 ? M5 : l == 5 ? M6 : M7;
    int s = 12 << l;
    float su = 0.f;
    for (int i = tid; i < s; i += 256) su += Mp[(long)i * s + i];
    red[tid] = su;
    __syncthreads();
    for (int st = 128; st > 0; st >>= 1) {
      if (tid < st) red[tid] += red[tid + st];
      __syncthreads();
    }
    if (tid == 0) TR[l] = red[0];
  } else if (bid < 3143) {
    int idx = (bid - 3079) * 256 + tid;
    int n = idx >> 6, k = idx & 63;
    CWT1[idx] = __float2bfloat16(k < 54 ? cw1[k * 256 + n] : 0.f);
  } else if (bid < 3271) {
    int idx = (bid - 3143) * 256 + tid;
    int n = idx >> 7, k = idx & 127;
    CWT2[idx] = __float2bfloat16(k < 108 ? cw2[k * 256 + n] : 0.f);
  } else if (bid < 3287) {
    int idx = (bid - 3271) * 256 + tid;
    int c = idx >> 8, k = idx & 255;
    DWT1[idx] = __float2bfloat16(c < 6 ? dw1[k * 6 + c] : 0.f);
  } else {
    int idx = (bid - 3287) * 256 + tid;
    int c = idx >> 8, k = idx & 255;
    DWT2[idx] = __float2bfloat16(c < 12 ? dw2[k * 12 + c] : 0.f);
  }
}

// ---- levels 1-4: in-block Taylor chain, M in LDS; reads prev via s2d map ----
__global__ __launch_bounds__(256) void expm_apply_kernel(
    const float* __restrict__ prev, const float* __restrict__ Mt,
    const float* __restrict__ eb, float* __restrict__ xblk,
    int s, int Cp, int h, int J, int tvs) {
  extern __shared__ float lds[];
  float* MtS = lds;
  float* Tb = lds + s * s;
  for (int i = threadIdx.x; i < s * s; i += 256) MtS[i] = Mt[i];

  int TV = 1 << tvs;
  int v = threadIdx.x >> tvs;
  int p = threadIdx.x & (TV - 1);
  int c0 = p * 6;
  int NV = 256 >> tvs;
  int sp = s + 1;
  int vec = blockIdx.x * NV + v;
  int hw = h * h;
  int b = vec / hw, rem = vec - b * hw;
  int y = rem / h, x = rem - (rem / h) * h;
  int W2 = 2 * h;
  long rowbase = ((long)(b * W2 + 2 * y) * W2 + 2 * x) * Cp;

  float acc[6];
#pragma unroll
  for (int m = 0; m < 6; m++) {
    int c = c0 + m;
    int q = c / Cp, cp = c - q * Cp;
    float xv = prev[rowbase + (long)((q >> 1) * W2 + (q & 1)) * Cp + cp] - eb[c];
    acc[m] = xv;
    Tb[v * sp + c0 + m] = xv;
  }
  __syncthreads();

  for (int j = 1; j <= J; j++) {
    float inv = 1.0f / (float)j;
    float tn[6] = {0.f, 0.f, 0.f, 0.f, 0.f, 0.f};
    const float* Trow = Tb + v * sp;
    for (int k = 0; k < s; k++) {
      float tv = Trow[k];
      const float* mrow = MtS + k * s + c0;
#pragma unroll
      for (int m = 0; m < 6; m++) tn[m] = fmaf(mrow[m], tv, tn[m]);
    }
    __syncthreads();
#pragma unroll
    for (int m = 0; m < 6; m++) {
      float t2 = tn[m] * inv;
      acc[m] += t2;
      Tb[v * sp + c0 + m] = t2;
    }
    __syncthreads();
  }

  float* xo = xblk + (long)vec * s;
#pragma unroll
  for (int m = 0; m < 6; m++) xo[c0 + m] = acc[m];
}

// ---- level 5 (S=192): fused Taylor chain, full M row in regs (96 VGPR) ----
template <int S>
__global__ __launch_bounds__(S, 2) void expm_chain_kernel(
    const float* __restrict__ prev, const __hip_bfloat16* __restrict__ Mrow,
    const float* __restrict__ eb, float* __restrict__ xblk,
    int Cp, int h, int J) {
  constexpr int NU4 = S / 8;
  __shared__ float tbuf[2][S];
  int c = threadIdx.x;
  int vec = blockIdx.x;
  int hw = h * h, W2 = 2 * h;
  int b = vec / hw, rem = vec - b * hw;
  int y = rem / h, x = rem - (rem / h) * h;
  int q = c / Cp, cp = c - q * Cp;
  long a = ((long)(b * W2 + 2 * y + (q >> 1)) * W2 + 2 * x + (q & 1)) * Cp + cp;

  uint4 mreg[NU4];
  const uint4* rp = (const uint4*)(Mrow + (long)c * S);
#pragma unroll
  for (int k8 = 0; k8 < NU4; k8++) mreg[k8] = rp[k8];

  float v = prev[a] - eb[c];
  float acc = v;
  tbuf[0][c] = v;
  __syncthreads();

  int cur = 0;
  for (int j = 1; j <= J; j++) {
    float inv = 1.0f / (float)j;
    float sacc[4] = {0.f, 0.f, 0.f, 0.f};
    const float* t = tbuf[cur];
#pragma unroll
    for (int k8 = 0; k8 < NU4; k8++) {
      uint4 u = mreg[k8];
      const float* tt = t + (k8 << 3);
      float ss = sacc[k8 & 3];
      ss = fmaf(__uint_as_float(u.x << 16), tt[0], ss);
      ss = fmaf(__uint_as_float(u.x & 0xffff0000u), tt[1], ss);
      ss = fmaf(__uint_as_float(u.y << 16), tt[2], ss);
      ss = fmaf(__uint_as_float(u.y & 0xffff0000u), tt[3], ss);
      ss = fmaf(__uint_as_float(u.z << 16), tt[4], ss);
      ss = fmaf(__uint_as_float(u.z & 0xffff0000u), tt[5], ss);
      ss = fmaf(__uint_as_float(u.w << 16), tt[6], ss);
      ss = fmaf(__uint_as_float(u.w & 0xffff0000u), tt[7], ss);
      sacc[k8 & 3] = ss;
    }
    float tn = ((sacc[0] + sacc[1]) + (sacc[2] + sacc[3])) * inv;
    acc += tn;
    cur ^= 1;
    tbuf[cur][c] = tn;
    __syncthreads();
  }
  xblk[(long)vec * S + c] = acc;
}

// ---- levels 6-7: per-term Taylor (streaming M from L2; allocator-proof) ----
__global__ __launch_bounds__(64) void expm_init_kernel(
    const float* __restrict__ prev, const float* __restrict__ eb,
    float* __restrict__ tcur, float* __restrict__ acc, int s, int Cp, int h,
    int nvec) {
  int total = nvec * s;
  int hw = h * h, W2 = 2 * h;
  for (int idx = blockIdx.x * 64 + threadIdx.x; idx < total;
       idx += gridDim.x * 64) {
    int v = idx / s, c = idx - (idx / s) * s;
    int b = v / hw, rem = v - b * hw;
    int y = rem / h, x = rem - (rem / h) * h;
    int q = c / Cp, cp = c - q * Cp;
    long a = ((long)(b * W2 + 2 * y + (q >> 1)) * W2 + 2 * x + (q & 1)) * Cp + cp;
    float xv = prev[a] - eb[c];
    tcur[idx] = xv;
    acc[idx] = xv;
  }
}

template <int S>
__global__ __launch_bounds__(64) void taylor_term_kernel(
    const __hip_bfloat16* __restrict__ Mrow, const float* __restrict__ t_old,
    float* __restrict__ t_new, float* __restrict__ acc, float inv_j) {
  __shared__ float tv[S];
  int tid = threadIdx.x;
  int v = blockIdx.y;
  int c = blockIdx.x * 64 + tid;
  const float4* t4 = (const float4*)(t_old + (long)v * S);
  float4* l4 = (float4*)tv;
  for (int i = tid; i < S / 4; i += 64) l4[i] = t4[i];
  __syncthreads();

  const uint4* rp = (const uint4*)(Mrow + (long)c * S);
  float sacc[4] = {0.f, 0.f, 0.f, 0.f};
#pragma unroll
  for (int k8 = 0; k8 < S / 8; k8++) {
    uint4 u = rp[k8];
    const float* tt = tv + (k8 << 3);
    float ss = sacc[k8 & 3];
    ss = fmaf(__uint_as_float(u.x << 16), tt[0], ss);
    ss = fmaf(__uint_as_float(u.x & 0xffff0000u), tt[1], ss);
    ss = fmaf(__uint_as_float(u.y << 16), tt[2], ss);
    ss = fmaf(__uint_as_float(u.y & 0xffff0000u), tt[3], ss);
    ss = fmaf(__uint_as_float(u.z << 16), tt[4], ss);
    ss = fmaf(__uint_as_float(u.z & 0xffff0000u), tt[5], ss);
    ss = fmaf(__uint_as_float(u.w << 16), tt[6], ss);
    ss = fmaf(__uint_as_float(u.w & 0xffff0000u), tt[7], ss);
    sacc[k8 & 3] = ss;
  }
  float tn = ((sacc[0] + sacc[1]) + (sacc[2] + sacc[3])) * inv_j;
  long o = (long)v * S + c;
  t_new[o] = tn;
  acc[o] += tn;
}

// ---- levels 1-2: MFMA implicit-GEMM conv3x3(D->256) + relu + dense(256->D)
template <int D, int KSTEPS>
__global__ __launch_bounds__(256, 3) void conv_dense_mfma(
    const float* __restrict__ xblk, float* __restrict__ xout,
    const __hip_bfloat16* __restrict__ cwT, const float* __restrict__ cb,
    const __hip_bfloat16* __restrict__ dwT, const float* __restrict__ db,
    const float* __restrict__ prev, int h, int s, int Cfull, int Cp, int pass) {
  constexpr int K9 = 9 * D;
  constexpr int KP = KSTEPS * 32;
  constexpr int KS = KP + 8;
  constexpr int HS = 264;
  extern __shared__ __hip_bfloat16 uls[];
  __hip_bfloat16* A = uls;
  __hip_bfloat16* H = uls + 64 * KS;
  float* cbS = (float*)(uls + 64 * KS + 64 * HS);

  int w = h;
  int tilesX = w >> 3;
  int bt = blockIdx.x;
  int tx = bt % tilesX; int t1 = bt / tilesX;
  int ty = t1 % tilesX; int b = t1 / tilesX;
  int y0 = ty * 8, x0 = tx * 8;
  int tid = threadIdx.x;

  cbS[tid] = cb[tid];

#pragma unroll
  for (int it = 0; it < 3; ++it) {
    int idx = it * 256 + tid;
    if (idx < 576) {
      int m = idx / 9, t = idx - m * 9;
      int ky = t / 3, kx = t - ky * 3;
      int pr = m >> 3, pc = m & 7;
      int iy = y0 + pr + ky - 1, ix = x0 + pc + kx - 1;
      unsigned* dst = (unsigned*)&A[m * KS + t * D];
      if (iy >= 0 && iy < h && ix >= 0 && ix < w) {
        const float* src = &xblk[((long)((b * h + iy) * w + ix)) * s];
        if constexpr (D == 6) {
          float4 p0 = *(const float4*)src;
          float2 p1 = *(const float2*)(src + 4);
          dst[0] = pkbf(p0.x, p0.y);
          dst[1] = pkbf(p0.z, p0.w);
          dst[2] = pkbf(p1.x, p1.y);
        } else {
          float4 p0 = ((const float4*)src)[0];
          float4 p1 = ((const float4*)src)[1];
          float4 p2 = ((const float4*)src)[2];
          dst[0] = pkbf(p0.x, p0.y);
          dst[1] = pkbf(p0.z, p0.w);
          dst[2] = pkbf(p1.x, p1.y);
          dst[3] = pkbf(p1.z, p1.w);
          dst[4] = pkbf(p2.x, p2.y);
          dst[5] = pkbf(p2.z, p2.w);
        }
      } else {
#pragma unroll
        for (int j = 0; j < D / 2; j++) dst[j] = 0u;
      }
    }
  }
  constexpr int PADU = (KP - K9) / 2;
  for (int idx = tid; idx < 64 * PADU; idx += 256) {
    int m = idx / PADU, j = idx - m * PADU;
    ((unsigned*)&A[m * KS + K9])[j] = 0u;
  }
  __syncthreads();

  int wid = tid >> 6, lane = tid & 63;
  int ln = lane & 15, hi = lane >> 4;

  bf16x8 af[KSTEPS];
#pragma unroll
  for (int ks = 0; ks < KSTEPS; ks++)
    af[ks] = *(const bf16x8*)&A[(wid * 16 + ln) * KS + ks * 32 + hi * 8];

  const __hip_bfloat16* cwrow = cwT + ln * KP + hi * 8;
  bf16x8 bq[KSTEPS], bn[KSTEPS];
#pragma unroll
  for (int ks = 0; ks < KSTEPS; ks++)
    bq[ks] = *(const bf16x8*)&cwrow[ks * 32];
#pragma unroll 1
  for (int nt = 0; nt < 16; nt++) {
    if (nt < 15) {
#pragma unroll
      for (int ks = 0; ks < KSTEPS; ks++)
        bn[ks] = *(const bf16x8*)&cwrow[(nt + 1) * 16 * KP + ks * 32];
    }
    f32x4 acc = {0.f, 0.f, 0.f, 0.f};
#pragma unroll
    for (int ks = 0; ks < KSTEPS; ks++)
      acc = __builtin_amdgcn_mfma_f32_16x16x32_bf16(af[ks], bq[ks], acc, 0, 0, 0);
    float cbv = cbS[nt * 16 + ln];
#pragma unroll
    for (int r = 0; r < 4; r++) {
      float hv = fmaxf(acc[r] + cbv, 0.f);
      H[(wid * 16 + hi * 4 + r) * HS + nt * 16 + ln] = __float2bfloat16(hv);
    }
#pragma unroll
    for (int ks = 0; ks < KSTEPS; ks++) bq[ks] = bn[ks];
  }
  __syncthreads();

  f32x4 acc2 = {0.f, 0.f, 0.f, 0.f};
  const __hip_bfloat16* dwrow = dwT + ln * 256 + hi * 8;
#pragma unroll
  for (int ks = 0; ks < 8; ks++) {
    bf16x8 a2 = *(const bf16x8*)&H[(wid * 16 + ln) * HS + ks * 32 + hi * 8];
    bf16x8 b2 = *(const bf16x8*)&dwrow[ks * 32];
    acc2 = __builtin_amdgcn_mfma_f32_16x16x32_bf16(a2, b2, acc2, 0, 0, 0);
  }

  if (ln < D) {
    float dbv = db[ln];
#pragma unroll
    for (int r = 0; r < 4; r++) {
      int m = wid * 16 + hi * 4 + r;
      int pr = m >> 3, pc = m & 7;
      long pix = (long)((b * h + y0 + pr) * w + (x0 + pc));
      float sh = acc2[r] + dbv;
      float x0v = xblk[pix * s + ln];
      float x1v = xblk[pix * s + D + ln];
      xout[pix * Cfull + ln] = x0v;
      xout[pix * Cfull + D + ln] = x1v - sh;
    }
  }

  if (pass > 0) {
    int W2 = 2 * h;
    int nq = pass / Cp;
    int q0 = s / Cp;
    int tasks = 64 * nq;
    for (int idx = tid; idx < tasks; idx += 256) {
      int m = idx / nq, qi = idx - (idx / nq) * nq;
      int q = q0 + qi;
      int pr = m >> 3, pc = m & 7;
      int yy = y0 + pr, xx = x0 + pc;
      const float4* src = (const float4*)
          &prev[((long)(b * W2 + 2 * yy + (q >> 1)) * W2 + 2 * xx + (q & 1)) * Cp];
      float4* dst = (float4*)&xout[((long)((b * h + yy) * w + xx)) * Cfull + q * Cp];
      for (int j = 0; j < Cp / 4; j++) dst[j] = src[j];
    }
  }
}

// ---- level 3: fused conv+dense v3 (VALU) ----
template <int TH, int TW, int D>
__global__ __launch_bounds__(256) void conv_dense_v3(
    const float* __restrict__ xblk, float* __restrict__ xout,
    const float* __restrict__ cw, const float* __restrict__ cb,
    const float* __restrict__ dw, const float* __restrict__ db,
    const float* __restrict__ prev, int h, int s, int Cfull, int Cp, int pass) {
  constexpr int P = TH * TW;
  constexpr int PW = 8;
  constexpr int DP = D + 1;
  extern __shared__ float lds[];
  float* dwS = lds;
  float* hbufS = dwS + 256 * DP;
  float* scratch = hbufS + P * 257;
  float* patchS = scratch;

  int w = h;
  int tilesX = w / TW, tilesY = h / TH;
  int bt = blockIdx.x;
  int tx = bt % tilesX; int t1 = bt / tilesX;
  int ty = t1 % tilesY; int b = t1 / tilesY;
  int y0 = ty * TH, x0 = tx * TW;
  int tid = threadIdx.x;

  for (int idx = tid; idx < 256 * D; idx += 256) {
    int k = idx / D, c = idx % D;
    dwS[k * DP + c] = dw[idx];
  }

  constexpr int PATCHN = D * (TH + 2) * (TW + 2);
  for (int idx = tid; idx < PATCHN; idx += 256) {
    int ci = idx % D; int rest = idx / D;
    int px = rest % (TW + 2); int py = rest / (TW + 2);
    int iy = y0 + py - 1, ix = x0 + px - 1;
    float v = 0.f;
    if (iy >= 0 && iy < h && ix >= 0 && ix < w)
      v = xblk[((long)((b * h + iy) * w + ix)) * s + ci];
    patchS[(ci * (TH + 2) + py) * PW + px] = v;
  }
  __syncthreads();

  float acc[P];
  float cbk = cb[tid];
#pragma unroll
  for (int p = 0; p < P; p++) acc[p] = cbk;

  float wv[9];
#pragma unroll
  for (int t = 0; t < 9; t++) wv[t] = cw[(long)(t * D) * 256 + tid];

#pragma unroll 1
  for (int ci = 0; ci < D; ci++) {
    float wvn[9];
    if (ci + 1 < D) {
#pragma unroll
      for (int t = 0; t < 9; t++) wvn[t] = cw[(long)(t * D + ci + 1) * 256 + tid];
    }
    float r[TH + 2][6];
#pragma unroll
    for (int py = 0; py < TH + 2; py++) {
      const float* rp = &patchS[(ci * (TH + 2) + py) * PW];
#pragma unroll
      for (int u = 0; u < 6; u++) r[py][u] = rp[u];
    }
#pragma unroll
    for (int ky = 0; ky < 3; ky++)
#pragma unroll
      for (int kx = 0; kx < 3; kx++)
#pragma unroll
        for (int pr = 0; pr < TH; pr++)
#pragma unroll
          for (int pc = 0; pc < TW; pc++)
            acc[pr * TW + pc] =
                fmaf(r[pr + ky][pc + kx], wv[ky * 3 + kx], acc[pr * TW + pc]);
#pragma unroll
    for (int t = 0; t < 9; t++) wv[t] = wvn[t];
  }
#pragma unroll
  for (int p = 0; p < P; p++) hbufS[p * 257 + tid] = fmaxf(acc[p], 0.f);
  __syncthreads();

  {
    int p = tid & 15, kc = tid >> 4;
    float part[D];
#pragma unroll
    for (int c = 0; c < D; c++) part[c] = 0.f;
    const float* hrow = hbufS + p * 257 + kc * 16;
#pragma unroll
    for (int k = 0; k < 16; k++) {
      float hv = hrow[k];
      const float* dr = dwS + (kc * 16 + k) * DP;
#pragma unroll
      for (int c = 0; c < D; c++) part[c] = fmaf(hv, dr[c], part[c]);
    }
    __syncthreads();
    float* partial = scratch;
#pragma unroll
    for (int c = 0; c < D; c++) partial[(kc * 16 + p) * DP + c] = part[c];
  }
  __syncthreads();

  for (int idx = tid; idx < P * D; idx += 256) {
    int p = idx / D, c = idx % D;
    float sh = db[c];
    const float* pp = scratch + p * DP + c;
#pragma unroll
    for (int kc = 0; kc < 16; kc++) sh += pp[kc * 16 * DP];
    int pr = p / TW, pc = p % TW;
    long pix = (long)((b * h + y0 + pr) * w + (x0 + pc));
    float x0v = xblk[pix * s + c];
    float x1v = xblk[pix * s + D + c];
    xout[pix * Cfull + c] = x0v;
    xout[pix * Cfull + D + c] = x1v - sh;
  }

  if (pass > 0) {
    int W2 = 2 * h;
    for (int idx = tid; idx < P * pass; idx += 256) {
      int pp = idx / pass, c = 2 * D + idx - (idx / pass) * pass;
      int pr = pp / TW, pc = pp - (pp / TW) * TW;
      int yy = y0 + pr, xx = x0 + pc;
      int q = c / Cp, cp = c - q * Cp;
      long a = ((long)(b * W2 + 2 * yy + (q >> 1)) * W2 + 2 * xx + (q & 1)) * Cp + cp;
      xout[((long)((b * h + yy) * w + xx)) * Cfull + c] = prev[a];
    }
  }
}

// ---- levels 4-7: K-split conv (atomic on zeroed hbuf) + dense + passthrough
template <int PIX>
__global__ __launch_bounds__(256) void conv_part_kernel(
    const float* __restrict__ xblk, const float* __restrict__ cw,
    float* __restrict__ hbuf, int h, int d, int s, int chunk) {
  extern __shared__ float pt[];
  int w = h;
  int nine_d = 9 * d;
  int j0 = blockIdx.y * chunk;
  int j1 = min(j0 + chunk, nine_d);
  int clen = j1 - j0;
  int pg = blockIdx.x;
  int tid = threadIdx.x;

  for (int idx = tid; idx < PIX * clen; idx += 256) {
    int q = idx / clen, jj = idx % clen;
    int j = j0 + jj;
    int t = j / d, ci = j - t * d;
    int ky = t / 3, kx = t % 3;
    int p = pg * PIX + q;
    int b = p / (h * w); int rem = p - b * h * w;
    int y = rem / w, x = rem - y * w;
    int iy = y + ky - 1, ix = x + kx - 1;
    float v = 0.f;
    if (iy >= 0 && iy < h && ix >= 0 && ix < w)
      v = xblk[((long)((b * h + iy) * w + ix)) * s + ci];
    pt[idx] = v;
  }
  __syncthreads();

  float acc[PIX];
#pragma unroll
  for (int q = 0; q < PIX; q++) acc[q] = 0.f;
  const float* cwp = cw + (long)j0 * 256 + tid;
#pragma unroll 4
  for (int jj = 0; jj < clen; jj++) {
    float cwv = cwp[(long)jj * 256];
#pragma unroll
    for (int q = 0; q < PIX; q++) acc[q] = fmaf(pt[q * clen + jj], cwv, acc[q]);
  }
#pragma unroll
  for (int q = 0; q < PIX; q++)
    atomicAdd(&hbuf[((long)(pg * PIX + q)) * 256 + tid], acc[q]);
}

__global__ __launch_bounds__(256) void dense_shift_kernel(
    const float* __restrict__ xblk, const float* __restrict__ hbuf,
    float* __restrict__ xout, const float* __restrict__ dw,
    const float* __restrict__ db, const float* __restrict__ cb,
    const float* __restrict__ prev, int d, int s, int Cfull, int Cp, int pass,
    int h, int nvec) {
  __shared__ float cbS[256];
  cbS[threadIdx.x] = cb[threadIdx.x];
  __syncthreads();
  int shiftN = nvec * d;
  for (int gid = blockIdx.x * 256 + threadIdx.x; gid < shiftN;
       gid += gridDim.x * 256) {
    int p = gid / d, c = gid - (gid / d) * d;
    float sum = db[c];
    const float* hrow = hbuf + (long)p * 256;
#pragma unroll 4
    for (int k = 0; k < 256; k++)
      sum = fmaf(fmaxf(hrow[k] + cbS[k], 0.f), dw[(long)k * d + c], sum);
    long pix = p;
    float x0v = xblk[pix * s + c];
    float x1v = xblk[pix * s + d + c];
    xout[pix * Cfull + c] = x0v;
    xout[pix * Cfull + d + c] = x1v - sum;
  }
  int hw = h * h, W2 = 2 * h;
  long passT = (long)nvec * pass;
  for (long e = blockIdx.x * 256 + threadIdx.x; e < passT;
       e += (long)gridDim.x * 256) {
    int p = (int)(e / pass);
    int c = s + (int)(e - (long)p * pass);
    int b = p / hw, rem = p - b * hw;
    int y = rem / h, x = rem - (rem / h) * h;
    int q = c / Cp, cp = c - q * Cp;
    long a = ((long)(b * W2 + 2 * y + (q >> 1)) * W2 + 2 * x + (q & 1)) * Cp + cp;
    xout[(long)p * Cfull + c] = prev[a];
  }
}

__global__ __launch_bounds__(256) void sumsq_kernel(const float* __restrict__ x,
                                                    float* __restrict__ part) {
  __shared__ float red[256];
  int b = blockIdx.x >> 6, ch = blockIdx.x & 63;
  const float* p = x + (long)b * 196608 + ch * 3072;
  float su = 0.f;
  for (int i = threadIdx.x; i < 3072; i += 256) {
    float v = p[i];
    su = fmaf(v, v, su);
  }
  red[threadIdx.x] = su;
  __syncthreads();
  for (int st = 128; st > 0; st >>= 1) {
    if (threadIdx.x < st) red[threadIdx.x] += red[threadIdx.x + st];
    __syncthreads();
  }
  if (threadIdx.x == 0) part[blockIdx.x] = red[0];
}

__global__ __launch_bounds__(256) void finalize_kernel(
    const float* __restrict__ part, const float* __restrict__ TR,
    float* __restrict__ out) {
  int tid = threadIdx.x;
  if (tid < 8) {
    float su = 0.f;
    for (int c = 0; c < 64; c++) su += part[tid * 64 + c];
    float ildj = 0.f;
    const float Hsq[7] = {16384.f, 4096.f, 1024.f, 256.f, 64.f, 16.f, 4.f};
#pragma unroll
    for (int i = 0; i < 7; i++) ildj += expf(TR[i]) * Hsq[i];
    out[tid] = -0.5f * su - 0.5f * 196608.0f * 1.8378770664093453f + ildj;
  }
}

extern "C" void kernel_launch(void* const* d_in, const int* in_sizes, int n_in,
                              void* d_out, int out_size, void* d_ws, size_t ws_size,
                              hipStream_t stream) {
  (void)in_sizes; (void)n_in; (void)out_size;
  const size_t need =
      ((size_t)3 * NXEL + 2 * 98304 + 387072 + 8 + 512) * sizeof(float);
  if (ws_size < need) return;

  const float* sample = (const float*)d_in[0];
  float* ws = (float*)d_ws;
  float* Xa = ws;
  float* Xb = Xa + NXEL;
  float* XBLK = Xb + NXEL;
  float* HBUF = XBLK + 262144;
  float* TCUR = XBLK + NXEL;
  float* MT = TCUR;
  __hip_bfloat16* CWT1 = (__hip_bfloat16*)(TCUR + 12240);
  __hip_bfloat16* CWT2 = (__hip_bfloat16*)(TCUR + 20432);
  __hip_bfloat16* DWT1 = (__hip_bfloat16*)(TCUR + 36816);
  __hip_bfloat16* DWT2 = (__hip_bfloat16*)(TCUR + 38864);
  float* TNXT = TCUR + 98304;
  __hip_bfloat16* MTB = (__hip_bfloat16*)(TNXT + 98304);
  float* TR = (float*)(MTB + 774144);
  float* PART = TR + 8;
  float* out = (float*)d_out;

  const float* Mp[7];
  const float *ebp[7], *cwp[7], *cbp[7], *dwp[7], *dbp[7];
  for (int i = 0; i < 7; i++) {
    Mp[i] = (const float*)d_in[1 + 6 * i + 0];
    ebp[i] = (const float*)d_in[1 + 6 * i + 1];
    cwp[i] = (const float*)d_in[1 + 6 * i + 2];
    cbp[i] = (const float*)d_in[1 + 6 * i + 3];
    dwp[i] = (const float*)d_in[1 + 6 * i + 4];
    dbp[i] = (const float*)d_in[1 + 6 * i + 5];
  }

  prep_all_kernel<<<3303, 256, 0, stream>>>(
      Mp[0], Mp[1], Mp[2], Mp[3], Mp[4], Mp[5], Mp[6], cwp[0], cwp[1], dwp[0],
      dwp[1], MT, MTB, TR, CWT1, CWT2, DWT1, DWT2);

  const int Jarr[7] = {5, 5, 6, 7, 7, 8, 10};
  const int MTOFF[4] = {0, 144, 720, 3024};
  const int MTBOFF[3] = {0, 36864, 184320};
  const int PIXa[7] = {0, 0, 0, 8, 8, 4, 2};
  const int KCa[7] = {0, 0, 0, 4, 16, 32, 64};

  int C = 3;
  for (int i = 0; i < 7; i++) {
    int s = 12 << i, d = s >> 1, h = 128 >> i;
    int Cp = C;
    int Cfull = 4 * C;
    int pass = Cfull - s;
    int nvec = 8 * h * h;
    float* xs2d = (i & 1) ? Xb : Xa;
    const float* prev = (i == 0) ? sample : ((i & 1) ? Xa : Xb);

    if (s <= 96) {
      int tvs = i + 1;
      int NV = 256 >> tvs;
      int ldsB = (s * s + NV * (s + 1)) * 4;
      expm_apply_kernel<<<nvec / NV, 256, ldsB, stream>>>(
          prev, MT + MTOFF[i], ebp[i], XBLK, s, Cp, h, Jarr[i], tvs);
    } else if (i == 4) {
      expm_chain_kernel<192><<<nvec, 192, 0, stream>>>(
          prev, MTB + MTBOFF[0], ebp[i], XBLK, Cp, h, Jarr[i]);
    } else {
      // i==5 (S=384) / i==6 (S=768): per-term streaming Taylor
      expm_init_kernel<<<384, 64, 0, stream>>>(prev, ebp[i], TCUR, XBLK, s, Cp,
                                               h, nvec);
      float* ta = TCUR;
      float* tb = TNXT;
      dim3 g(s / 64, nvec);
      for (int j = 1; j <= Jarr[i]; j++) {
        if (i == 5)
          taylor_term_kernel<384><<<g, 64, 0, stream>>>(
              MTB + MTBOFF[1], ta, tb, XBLK, 1.0f / (float)j);
        else
          taylor_term_kernel<768><<<g, 64, 0, stream>>>(
              MTB + MTBOFF[2], ta, tb, XBLK, 1.0f / (float)j);
        float* tmp = ta; ta = tb; tb = tmp;
      }
    }

    if (i == 0) {
      int blocks = 8 * (h / 8) * (h / 8);
      int ldsB = (64 * (64 + 8) + 64 * 264) * 2 + 1024;
      conv_dense_mfma<6, 2><<<blocks, 256, ldsB, stream>>>(
          XBLK, xs2d, CWT1, cbp[0], DWT1, dbp[0], prev, h, s, Cfull, Cp, pass);
    } else if (i == 1) {
      int blocks = 8 * (h / 8) * (h / 8);
      int ldsB = (64 * (128 + 8) + 64 * 264) * 2 + 1024;
      conv_dense_mfma<12, 4><<<blocks, 256, ldsB, stream>>>(
          XBLK, xs2d, CWT2, cbp[1], DWT2, dbp[1], prev, h, s, Cfull, Cp, pass);
    } else if (i == 2) {
      int blocks = 8 * (h / 4) * (h / 4);
      int ldsB = (2 * 256 * (d + 1) + 16 * 257) * 4;
      conv_dense_v3<4, 4, 24><<<blocks, 256, ldsB, stream>>>(
          XBLK, xs2d, cwp[i], cbp[i], dwp[i], dbp[i], prev, h, s, Cfull, Cp, pass);
    } else {
      hipMemsetAsync(HBUF, 0, (size_t)nvec * 256 * 4, stream);
      int PIX = PIXa[i], KC = KCa[i];
      int nine_d = 9 * d;
      int chunk = (nine_d + KC - 1) / KC;
      dim3 ga(nvec / PIX, KC);
      int alds = PIX * chunk * 4;
      if (PIX == 8)
        conv_part_kernel<8><<<ga, 256, alds, stream>>>(XBLK, cwp[i], HBUF, h, d, s, chunk);
      else if (PIX == 4)
        conv_part_kernel<4><<<ga, 256, alds, stream>>>(XBLK, cwp[i], HBUF, h, d, s, chunk);
      else
        conv_part_kernel<2><<<ga, 256, alds, stream>>>(XBLK, cwp[i], HBUF, h, d, s, chunk);
      long shiftN = (long)nvec * d, passT = (long)nvec * pass;
      int dsb = (int)((shiftN + 255) / 256 + (passT + 255) / 256);
      if (dsb > 4096) dsb = 4096;
      dense_shift_kernel<<<dsb, 256, 0, stream>>>(
          XBLK, HBUF, xs2d, dwp[i], dbp[i], cbp[i], prev, d, s, Cfull, Cp, pass,
          h, nvec);
    }
    C = Cfull;
  }

  sumsq_kernel<<<512, 256, 0, stream>>>(Xa, PART);
  finalize_kernel<<<1, 256, 0, stream>>>(PART, TR, out);
}

// Round 17
// 487.715 us; speedup vs baseline: 1.0016x; 1.0016x over previous
//
#include <hip/hip_runtime.h>
#include <hip/hip_bf16.h>
#include <math.h>

// Flow log_prob. R17: conv_dense_mfma drops the H LDS buffer + dense MFMA.
// R16 diagnosis: 44KB LDS (H=34KB) -> 3 blocks/CU, VGPR=28 -> bq/bn prefetch
// serialized into 16 L2 round-trips -> 85% stall. Dense(256->D, D<=12) is now
// VALU in-loop: lane holds h[m][k=nt*16+ln] in the conv C-frag; accumulate
// part[r][c] += relu(h)*dw[k][c] (LDS broadcast reads), butterfly-reduce over
// ln, lane ln==0 writes. LDS 16/30KB -> 8/5 blocks/CU.

#define NXEL 1572864  // 8*256*256*3

typedef __attribute__((ext_vector_type(8))) short bf16x8;
typedef __attribute__((ext_vector_type(4))) float f32x4;

__device__ inline unsigned pkbf(float a, float b) {
  union { __hip_bfloat16 h; unsigned short u; } ca, cb2;
  ca.h = __float2bfloat16(a);
  cb2.h = __float2bfloat16(b);
  return (unsigned)ca.u | ((unsigned)cb2.u << 16);
}

// ---------- one-shot prep ----------
__global__ __launch_bounds__(256) void prep_all_kernel(
    const float* __restrict__ M1, const float* __restrict__ M2,
    const float* __restrict__ M3, const float* __restrict__ M4,
    const float* __restrict__ M5, const float* __restrict__ M6,
    const float* __restrict__ M7, const float* __restrict__ cw1,
    const float* __restrict__ cw2, float* __restrict__ MT,
    __hip_bfloat16* __restrict__ MTB, float* __restrict__ TR,
    __hip_bfloat16* __restrict__ CWT1, __hip_bfloat16* __restrict__ CWT2) {
  int bid = blockIdx.x, tid = threadIdx.x;
  if (bid < 48) {
    int idx = bid * 256 + tid;
    if (idx < 12240) {
      const int cum[5] = {0, 144, 720, 3024, 12240};
      int l = 0;
      while (idx >= cum[l + 1]) l++;
      int local = idx - cum[l];
      int s = 12 << l;
      int k = local / s, c = local - k * s;
      const float* Mp = l == 0 ? M1 : l == 1 ? M2 : l == 2 ? M3 : M4;
      MT[idx] = -Mp[c * s + k];
    }
  } else if (bid < 3072) {
    int idx = (bid - 48) * 256 + tid;
    if (idx < 774144) {
      const int cum[4] = {0, 36864, 184320, 774144};
      int l = 0;
      while (idx >= cum[l + 1]) l++;
      const float* Mp = l == 0 ? M5 : l == 1 ? M6 : M7;
      MTB[idx] = __float2bfloat16(-Mp[idx - cum[l]]);
    }
  } else if (bid < 3079) {
    __shared__ float red[256];
    int l = bid - 3072;
    const float* Mp = l == 0 ? M1 : l == 1 ? M2 : l == 2 ? M3 : l == 3 ? M4
                    : l == 4 ? M5 : l == 5 ? M6 : M7;
    int s = 12 << l;
    float su = 0.f;
    for (int i = tid; i < s; i += 256) su += Mp[(long)i * s + i];
    red[tid] = su;
    __syncthreads();
    for (int st = 128; st > 0; st >>= 1) {
      if (tid < st) red[tid] += red[tid + st];
      __syncthreads();
    }
    if (tid == 0) TR[l] = red[0];
  } else if (bid < 3143) {
    int idx = (bid - 3079) * 256 + tid;
    int n = idx >> 6, k = idx & 63;
    CWT1[idx] = __float2bfloat16(k < 54 ? cw1[k * 256 + n] : 0.f);
  } else {
    int idx = (bid - 3143) * 256 + tid;
    int n = idx >> 7, k = idx & 127;
    CWT2[idx] = __float2bfloat16(k < 108 ? cw2[k * 256 + n] : 0.f);
  }
}

// ---- levels 1-4: in-block Taylor chain, M in LDS; reads prev via s2d map ----
__global__ __launch_bounds__(256) void expm_apply_kernel(
    const float* __restrict__ prev, const float* __restrict__ Mt,
    const float* __restrict__ eb, float* __restrict__ xblk,
    int s, int Cp, int h, int J, int tvs) {
  extern __shared__ float lds[];
  float* MtS = lds;
  float* Tb = lds + s * s;
  for (int i = threadIdx.x; i < s * s; i += 256) MtS[i] = Mt[i];

  int TV = 1 << tvs;
  int v = threadIdx.x >> tvs;
  int p = threadIdx.x & (TV - 1);
  int c0 = p * 6;
  int NV = 256 >> tvs;
  int sp = s + 1;
  int vec = blockIdx.x * NV + v;
  int hw = h * h;
  int b = vec / hw, rem = vec - b * hw;
  int y = rem / h, x = rem - (rem / h) * h;
  int W2 = 2 * h;
  long rowbase = ((long)(b * W2 + 2 * y) * W2 + 2 * x) * Cp;

  float acc[6];
#pragma unroll
  for (int m = 0; m < 6; m++) {
    int c = c0 + m;
    int q = c / Cp, cp = c - q * Cp;
    float xv = prev[rowbase + (long)((q >> 1) * W2 + (q & 1)) * Cp + cp] - eb[c];
    acc[m] = xv;
    Tb[v * sp + c0 + m] = xv;
  }
  __syncthreads();

  for (int j = 1; j <= J; j++) {
    float inv = 1.0f / (float)j;
    float tn[6] = {0.f, 0.f, 0.f, 0.f, 0.f, 0.f};
    const float* Trow = Tb + v * sp;
    for (int k = 0; k < s; k++) {
      float tv = Trow[k];
      const float* mrow = MtS + k * s + c0;
#pragma unroll
      for (int m = 0; m < 6; m++) tn[m] = fmaf(mrow[m], tv, tn[m]);
    }
    __syncthreads();
#pragma unroll
    for (int m = 0; m < 6; m++) {
      float t2 = tn[m] * inv;
      acc[m] += t2;
      Tb[v * sp + c0 + m] = t2;
    }
    __syncthreads();
  }

  float* xo = xblk + (long)vec * s;
#pragma unroll
  for (int m = 0; m < 6; m++) xo[c0 + m] = acc[m];
}

// ---- level 5 (S=192): fused Taylor chain, full M row in regs (96 VGPR) ----
template <int S>
__global__ __launch_bounds__(S, 2) void expm_chain_kernel(
    const float* __restrict__ prev, const __hip_bfloat16* __restrict__ Mrow,
    const float* __restrict__ eb, float* __restrict__ xblk,
    int Cp, int h, int J) {
  constexpr int NU4 = S / 8;
  __shared__ float tbuf[2][S];
  int c = threadIdx.x;
  int vec = blockIdx.x;
  int hw = h * h, W2 = 2 * h;
  int b = vec / hw, rem = vec - b * hw;
  int y = rem / h, x = rem - (rem / h) * h;
  int q = c / Cp, cp = c - q * Cp;
  long a = ((long)(b * W2 + 2 * y + (q >> 1)) * W2 + 2 * x + (q & 1)) * Cp + cp;

  uint4 mreg[NU4];
  const uint4* rp = (const uint4*)(Mrow + (long)c * S);
#pragma unroll
  for (int k8 = 0; k8 < NU4; k8++) mreg[k8] = rp[k8];

  float v = prev[a] - eb[c];
  float acc = v;
  tbuf[0][c] = v;
  __syncthreads();

  int cur = 0;
  for (int j = 1; j <= J; j++) {
    float inv = 1.0f / (float)j;
    float sacc[4] = {0.f, 0.f, 0.f, 0.f};
    const float* t = tbuf[cur];
#pragma unroll
    for (int k8 = 0; k8 < NU4; k8++) {
      uint4 u = mreg[k8];
      const float* tt = t + (k8 << 3);
      float ss = sacc[k8 & 3];
      ss = fmaf(__uint_as_float(u.x << 16), tt[0], ss);
      ss = fmaf(__uint_as_float(u.x & 0xffff0000u), tt[1], ss);
      ss = fmaf(__uint_as_float(u.y << 16), tt[2], ss);
      ss = fmaf(__uint_as_float(u.y & 0xffff0000u), tt[3], ss);
      ss = fmaf(__uint_as_float(u.z << 16), tt[4], ss);
      ss = fmaf(__uint_as_float(u.z & 0xffff0000u), tt[5], ss);
      ss = fmaf(__uint_as_float(u.w << 16), tt[6], ss);
      ss = fmaf(__uint_as_float(u.w & 0xffff0000u), tt[7], ss);
      sacc[k8 & 3] = ss;
    }
    float tn = ((sacc[0] + sacc[1]) + (sacc[2] + sacc[3])) * inv;
    acc += tn;
    cur ^= 1;
    tbuf[cur][c] = tn;
    __syncthreads();
  }
  xblk[(long)vec * S + c] = acc;
}

// ---- levels 6-7: per-term Taylor (streaming M from L2; allocator-proof) ----
__global__ __launch_bounds__(64) void expm_init_kernel(
    const float* __restrict__ prev, const float* __restrict__ eb,
    float* __restrict__ tcur, float* __restrict__ acc, int s, int Cp, int h,
    int nvec) {
  int total = nvec * s;
  int hw = h * h, W2 = 2 * h;
  for (int idx = blockIdx.x * 64 + threadIdx.x; idx < total;
       idx += gridDim.x * 64) {
    int v = idx / s, c = idx - (idx / s) * s;
    int b = v / hw, rem = v - b * hw;
    int y = rem / h, x = rem - (rem / h) * h;
    int q = c / Cp, cp = c - q * Cp;
    long a = ((long)(b * W2 + 2 * y + (q >> 1)) * W2 + 2 * x + (q & 1)) * Cp + cp;
    float xv = prev[a] - eb[c];
    tcur[idx] = xv;
    acc[idx] = xv;
  }
}

template <int S>
__global__ __launch_bounds__(64) void taylor_term_kernel(
    const __hip_bfloat16* __restrict__ Mrow, const float* __restrict__ t_old,
    float* __restrict__ t_new, float* __restrict__ acc, float inv_j) {
  __shared__ float tv[S];
  int tid = threadIdx.x;
  int v = blockIdx.y;
  int c = blockIdx.x * 64 + tid;
  const float4* t4 = (const float4*)(t_old + (long)v * S);
  float4* l4 = (float4*)tv;
  for (int i = tid; i < S / 4; i += 64) l4[i] = t4[i];
  __syncthreads();

  const uint4* rp = (const uint4*)(Mrow + (long)c * S);
  float sacc[4] = {0.f, 0.f, 0.f, 0.f};
#pragma unroll
  for (int k8 = 0; k8 < S / 8; k8++) {
    uint4 u = rp[k8];
    const float* tt = tv + (k8 << 3);
    float ss = sacc[k8 & 3];
    ss = fmaf(__uint_as_float(u.x << 16), tt[0], ss);
    ss = fmaf(__uint_as_float(u.x & 0xffff0000u), tt[1], ss);
    ss = fmaf(__uint_as_float(u.y << 16), tt[2], ss);
    ss = fmaf(__uint_as_float(u.y & 0xffff0000u), tt[3], ss);
    ss = fmaf(__uint_as_float(u.z << 16), tt[4], ss);
    ss = fmaf(__uint_as_float(u.z & 0xffff0000u), tt[5], ss);
    ss = fmaf(__uint_as_float(u.w << 16), tt[6], ss);
    ss = fmaf(__uint_as_float(u.w & 0xffff0000u), tt[7], ss);
    sacc[k8 & 3] = ss;
  }
  float tn = ((sacc[0] + sacc[1]) + (sacc[2] + sacc[3])) * inv_j;
  long o = (long)v * S + c;
  t_new[o] = tn;
  acc[o] += tn;
}

// ---- levels 1-2: MFMA conv3x3(D->256) + in-loop VALU dense(256->D) ----
// Lane (wid,hi,ln): conv C-frag holds h[m=wid*16+hi*4+r][k=nt*16+ln].
// part[r][c] += relu(h)*dwS[k][c]; butterfly over ln; ln==0 writes shift.
template <int D, int KSTEPS>
__global__ __launch_bounds__(256) void conv_dense_mfma(
    const float* __restrict__ xblk, float* __restrict__ xout,
    const __hip_bfloat16* __restrict__ cwT, const float* __restrict__ cb,
    const float* __restrict__ dw, const float* __restrict__ db,
    const float* __restrict__ prev, int h, int s, int Cfull, int Cp, int pass) {
  constexpr int K9 = 9 * D;
  constexpr int KP = KSTEPS * 32;
  constexpr int KS = KP + 8;
  extern __shared__ __hip_bfloat16 uls[];
  __hip_bfloat16* A = uls;                    // [64][KS]
  float* dwS = (float*)(uls + 64 * KS);       // [256][D]
  float* cbS = dwS + 256 * D;                 // [256]

  int w = h;
  int tilesX = w >> 3;
  int bt = blockIdx.x;
  int tx = bt % tilesX; int t1 = bt / tilesX;
  int ty = t1 % tilesX; int b = t1 / tilesX;
  int y0 = ty * 8, x0 = tx * 8;
  int tid = threadIdx.x;

  for (int idx = tid; idx < 256 * D; idx += 256) dwS[idx] = dw[idx];
  cbS[tid] = cb[tid];

#pragma unroll
  for (int it = 0; it < 3; ++it) {
    int idx = it * 256 + tid;
    if (idx < 576) {
      int m = idx / 9, t = idx - m * 9;
      int ky = t / 3, kx = t - ky * 3;
      int pr = m >> 3, pc = m & 7;
      int iy = y0 + pr + ky - 1, ix = x0 + pc + kx - 1;
      unsigned* dst = (unsigned*)&A[m * KS + t * D];
      if (iy >= 0 && iy < h && ix >= 0 && ix < w) {
        const float* src = &xblk[((long)((b * h + iy) * w + ix)) * s];
        if constexpr (D == 6) {
          float4 p0 = *(const float4*)src;
          float2 p1 = *(const float2*)(src + 4);
          dst[0] = pkbf(p0.x, p0.y);
          dst[1] = pkbf(p0.z, p0.w);
          dst[2] = pkbf(p1.x, p1.y);
        } else {
          float4 p0 = ((const float4*)src)[0];
          float4 p1 = ((const float4*)src)[1];
          float4 p2 = ((const float4*)src)[2];
          dst[0] = pkbf(p0.x, p0.y);
          dst[1] = pkbf(p0.z, p0.w);
          dst[2] = pkbf(p1.x, p1.y);
          dst[3] = pkbf(p1.z, p1.w);
          dst[4] = pkbf(p2.x, p2.y);
          dst[5] = pkbf(p2.z, p2.w);
        }
      } else {
#pragma unroll
        for (int j = 0; j < D / 2; j++) dst[j] = 0u;
      }
    }
  }
  constexpr int PADU = (KP - K9) / 2;
  for (int idx = tid; idx < 64 * PADU; idx += 256) {
    int m = idx / PADU, j = idx - m * PADU;
    ((unsigned*)&A[m * KS + K9])[j] = 0u;
  }
  __syncthreads();

  int wid = tid >> 6, lane = tid & 63;
  int ln = lane & 15, hi = lane >> 4;

  bf16x8 af[KSTEPS];
#pragma unroll
  for (int ks = 0; ks < KSTEPS; ks++)
    af[ks] = *(const bf16x8*)&A[(wid * 16 + ln) * KS + ks * 32 + hi * 8];

  const __hip_bfloat16* cwrow = cwT + ln * KP + hi * 8;
  bf16x8 bq[KSTEPS], bn[KSTEPS];
#pragma unroll
  for (int ks = 0; ks < KSTEPS; ks++)
    bq[ks] = *(const bf16x8*)&cwrow[ks * 32];

  float part[4][D];
#pragma unroll
  for (int r = 0; r < 4; r++)
#pragma unroll
    for (int c = 0; c < D; c++) part[r][c] = 0.f;

#pragma unroll 1
  for (int nt = 0; nt < 16; nt++) {
    if (nt < 15) {
#pragma unroll
      for (int ks = 0; ks < KSTEPS; ks++)
        bn[ks] = *(const bf16x8*)&cwrow[(nt + 1) * 16 * KP + ks * 32];
    }
    f32x4 acc = {0.f, 0.f, 0.f, 0.f};
#pragma unroll
    for (int ks = 0; ks < KSTEPS; ks++)
      acc = __builtin_amdgcn_mfma_f32_16x16x32_bf16(af[ks], bq[ks], acc, 0, 0, 0);
    int k = nt * 16 + ln;
    float cbv = cbS[k];
    const float* dr = dwS + k * D;
#pragma unroll
    for (int r = 0; r < 4; r++) {
      float hv = fmaxf(acc[r] + cbv, 0.f);
#pragma unroll
      for (int c = 0; c < D; c++) part[r][c] = fmaf(hv, dr[c], part[r][c]);
    }
#pragma unroll
    for (int ks = 0; ks < KSTEPS; ks++) bq[ks] = bn[ks];
  }

  // butterfly reduce over the 16 ln lanes (same hi group -> same m rows)
#pragma unroll
  for (int msk = 1; msk <= 8; msk <<= 1)
#pragma unroll
    for (int r = 0; r < 4; r++)
#pragma unroll
      for (int c = 0; c < D; c++)
        part[r][c] += __shfl_xor(part[r][c], msk, 64);

  if (ln == 0) {
#pragma unroll
    for (int r = 0; r < 4; r++) {
      int m = wid * 16 + hi * 4 + r;
      int pr = m >> 3, pc = m & 7;
      long pix = (long)((b * h + y0 + pr) * w + (x0 + pc));
#pragma unroll
      for (int c = 0; c < D; c++)
        xout[pix * Cfull + D + c] = xblk[pix * s + D + c] - (part[r][c] + db[c]);
    }
  }

  // x0 copy (channels [0,D)) by all threads
  for (int idx = tid; idx < 64 * D; idx += 256) {
    int m = idx / D, c = idx - (idx / D) * D;
    int pr = m >> 3, pc = m & 7;
    long pix = (long)((b * h + y0 + pr) * w + (x0 + pc));
    xout[pix * Cfull + c] = xblk[pix * s + c];
  }

  // passthrough [s, Cfull)
  if (pass > 0) {
    int W2 = 2 * h;
    int nq = pass / Cp;
    int q0 = s / Cp;
    int tasks = 64 * nq;
    for (int idx = tid; idx < tasks; idx += 256) {
      int m = idx / nq, qi = idx - (idx / nq) * nq;
      int q = q0 + qi;
      int pr = m >> 3, pc = m & 7;
      int yy = y0 + pr, xx = x0 + pc;
      const float4* src = (const float4*)
          &prev[((long)(b * W2 + 2 * yy + (q >> 1)) * W2 + 2 * xx + (q & 1)) * Cp];
      float4* dst = (float4*)&xout[((long)((b * h + yy) * w + xx)) * Cfull + q * Cp];
      for (int j = 0; j < Cp / 4; j++) dst[j] = src[j];
    }
  }
}

// ---- level 3: fused conv+dense v3 (VALU) ----
template <int TH, int TW, int D>
__global__ __launch_bounds__(256) void conv_dense_v3(
    const float* __restrict__ xblk, float* __restrict__ xout,
    const float* __restrict__ cw, const float* __restrict__ cb,
    const float* __restrict__ dw, const float* __restrict__ db,
    const float* __restrict__ prev, int h, int s, int Cfull, int Cp, int pass) {
  constexpr int P = TH * TW;
  constexpr int PW = 8;
  constexpr int DP = D + 1;
  extern __shared__ float lds[];
  float* dwS = lds;
  float* hbufS = dwS + 256 * DP;
  float* scratch = hbufS + P * 257;
  float* patchS = scratch;

  int w = h;
  int tilesX = w / TW, tilesY = h / TH;
  int bt = blockIdx.x;
  int tx = bt % tilesX; int t1 = bt / tilesX;
  int ty = t1 % tilesY; int b = t1 / tilesY;
  int y0 = ty * TH, x0 = tx * TW;
  int tid = threadIdx.x;

  for (int idx = tid; idx < 256 * D; idx += 256) {
    int k = idx / D, c = idx % D;
    dwS[k * DP + c] = dw[idx];
  }

  constexpr int PATCHN = D * (TH + 2) * (TW + 2);
  for (int idx = tid; idx < PATCHN; idx += 256) {
    int ci = idx % D; int rest = idx / D;
    int px = rest % (TW + 2); int py = rest / (TW + 2);
    int iy = y0 + py - 1, ix = x0 + px - 1;
    float v = 0.f;
    if (iy >= 0 && iy < h && ix >= 0 && ix < w)
      v = xblk[((long)((b * h + iy) * w + ix)) * s + ci];
    patchS[(ci * (TH + 2) + py) * PW + px] = v;
  }
  __syncthreads();

  float acc[P];
  float cbk = cb[tid];
#pragma unroll
  for (int p = 0; p < P; p++) acc[p] = cbk;

  float wv[9];
#pragma unroll
  for (int t = 0; t < 9; t++) wv[t] = cw[(long)(t * D) * 256 + tid];

#pragma unroll 1
  for (int ci = 0; ci < D; ci++) {
    float wvn[9];
    if (ci + 1 < D) {
#pragma unroll
      for (int t = 0; t < 9; t++) wvn[t] = cw[(long)(t * D + ci + 1) * 256 + tid];
    }
    float r[TH + 2][6];
#pragma unroll
    for (int py = 0; py < TH + 2; py++) {
      const float* rp = &patchS[(ci * (TH + 2) + py) * PW];
#pragma unroll
      for (int u = 0; u < 6; u++) r[py][u] = rp[u];
    }
#pragma unroll
    for (int ky = 0; ky < 3; ky++)
#pragma unroll
      for (int kx = 0; kx < 3; kx++)
#pragma unroll
        for (int pr = 0; pr < TH; pr++)
#pragma unroll
          for (int pc = 0; pc < TW; pc++)
            acc[pr * TW + pc] =
                fmaf(r[pr + ky][pc + kx], wv[ky * 3 + kx], acc[pr * TW + pc]);
#pragma unroll
    for (int t = 0; t < 9; t++) wv[t] = wvn[t];
  }
#pragma unroll
  for (int p = 0; p < P; p++) hbufS[p * 257 + tid] = fmaxf(acc[p], 0.f);
  __syncthreads();

  {
    int p = tid & 15, kc = tid >> 4;
    float part[D];
#pragma unroll
    for (int c = 0; c < D; c++) part[c] = 0.f;
    const float* hrow = hbufS + p * 257 + kc * 16;
#pragma unroll
    for (int k = 0; k < 16; k++) {
      float hv = hrow[k];
      const float* dr = dwS + (kc * 16 + k) * DP;
#pragma unroll
      for (int c = 0; c < D; c++) part[c] = fmaf(hv, dr[c], part[c]);
    }
    __syncthreads();
    float* partial = scratch;
#pragma unroll
    for (int c = 0; c < D; c++) partial[(kc * 16 + p) * DP + c] = part[c];
  }
  __syncthreads();

  for (int idx = tid; idx < P * D; idx += 256) {
    int p = idx / D, c = idx % D;
    float sh = db[c];
    const float* pp = scratch + p * DP + c;
#pragma unroll
    for (int kc = 0; kc < 16; kc++) sh += pp[kc * 16 * DP];
    int pr = p / TW, pc = p % TW;
    long pix = (long)((b * h + y0 + pr) * w + (x0 + pc));
    float x0v = xblk[pix * s + c];
    float x1v = xblk[pix * s + D + c];
    xout[pix * Cfull + c] = x0v;
    xout[pix * Cfull + D + c] = x1v - sh;
  }

  if (pass > 0) {
    int W2 = 2 * h;
    for (int idx = tid; idx < P * pass; idx += 256) {
      int pp = idx / pass, c = 2 * D + idx - (idx / pass) * pass;
      int pr = pp / TW, pc = pp - (pp / TW) * TW;
      int yy = y0 + pr, xx = x0 + pc;
      int q = c / Cp, cp = c - q * Cp;
      long a = ((long)(b * W2 + 2 * yy + (q >> 1)) * W2 + 2 * xx + (q & 1)) * Cp + cp;
      xout[((long)((b * h + yy) * w + xx)) * Cfull + c] = prev[a];
    }
  }
}

// ---- levels 4-7: K-split conv (atomic on zeroed hbuf) + dense + passthrough
template <int PIX>
__global__ __launch_bounds__(256) void conv_part_kernel(
    const float* __restrict__ xblk, const float* __restrict__ cw,
    float* __restrict__ hbuf, int h, int d, int s, int chunk) {
  extern __shared__ float pt[];
  int w = h;
  int nine_d = 9 * d;
  int j0 = blockIdx.y * chunk;
  int j1 = min(j0 + chunk, nine_d);
  int clen = j1 - j0;
  int pg = blockIdx.x;
  int tid = threadIdx.x;

  for (int idx = tid; idx < PIX * clen; idx += 256) {
    int q = idx / clen, jj = idx % clen;
    int j = j0 + jj;
    int t = j / d, ci = j - t * d;
    int ky = t / 3, kx = t % 3;
    int p = pg * PIX + q;
    int b = p / (h * w); int rem = p - b * h * w;
    int y = rem / w, x = rem - y * w;
    int iy = y + ky - 1, ix = x + kx - 1;
    float v = 0.f;
    if (iy >= 0 && iy < h && ix >= 0 && ix < w)
      v = xblk[((long)((b * h + iy) * w + ix)) * s + ci];
    pt[idx] = v;
  }
  __syncthreads();

  float acc[PIX];
#pragma unroll
  for (int q = 0; q < PIX; q++) acc[q] = 0.f;
  const float* cwp = cw + (long)j0 * 256 + tid;
#pragma unroll 4
  for (int jj = 0; jj < clen; jj++) {
    float cwv = cwp[(long)jj * 256];
#pragma unroll
    for (int q = 0; q < PIX; q++) acc[q] = fmaf(pt[q * clen + jj], cwv, acc[q]);
  }
#pragma unroll
  for (int q = 0; q < PIX; q++)
    atomicAdd(&hbuf[((long)(pg * PIX + q)) * 256 + tid], acc[q]);
}

__global__ __launch_bounds__(256) void dense_shift_kernel(
    const float* __restrict__ xblk, const float* __restrict__ hbuf,
    float* __restrict__ xout, const float* __restrict__ dw,
    const float* __restrict__ db, const float* __restrict__ cb,
    const float* __restrict__ prev, int d, int s, int Cfull, int Cp, int pass,
    int h, int nvec) {
  __shared__ float cbS[256];
  cbS[threadIdx.x] = cb[threadIdx.x];
  __syncthreads();
  int shiftN = nvec * d;
  for (int gid = blockIdx.x * 256 + threadIdx.x; gid < shiftN;
       gid += gridDim.x * 256) {
    int p = gid / d, c = gid - (gid / d) * d;
    float sum = db[c];
    const float* hrow = hbuf + (long)p * 256;
#pragma unroll 4
    for (int k = 0; k < 256; k++)
      sum = fmaf(fmaxf(hrow[k] + cbS[k], 0.f), dw[(long)k * d + c], sum);
    long pix = p;
    float x0v = xblk[pix * s + c];
    float x1v = xblk[pix * s + d + c];
    xout[pix * Cfull + c] = x0v;
    xout[pix * Cfull + d + c] = x1v - sum;
  }
  int hw = h * h, W2 = 2 * h;
  long passT = (long)nvec * pass;
  for (long e = blockIdx.x * 256 + threadIdx.x; e < passT;
       e += (long)gridDim.x * 256) {
    int p = (int)(e / pass);
    int c = s + (int)(e - (long)p * pass);
    int b = p / hw, rem = p - b * hw;
    int y = rem / h, x = rem - (rem / h) * h;
    int q = c / Cp, cp = c - q * Cp;
    long a = ((long)(b * W2 + 2 * y + (q >> 1)) * W2 + 2 * x + (q & 1)) * Cp + cp;
    xout[(long)p * Cfull + c] = prev[a];
  }
}

__global__ __launch_bounds__(256) void sumsq_kernel(const float* __restrict__ x,
                                                    float* __restrict__ part) {
  __shared__ float red[256];
  int b = blockIdx.x >> 6, ch = blockIdx.x & 63;
  const float* p = x + (long)b * 196608 + ch * 3072;
  float su = 0.f;
  for (int i = threadIdx.x; i < 3072; i += 256) {
    float v = p[i];
    su = fmaf(v, v, su);
  }
  red[threadIdx.x] = su;
  __syncthreads();
  for (int st = 128; st > 0; st >>= 1) {
    if (threadIdx.x < st) red[threadIdx.x] += red[threadIdx.x + st];
    __syncthreads();
  }
  if (threadIdx.x == 0) part[blockIdx.x] = red[0];
}

__global__ __launch_bounds__(256) void finalize_kernel(
    const float* __restrict__ part, const float* __restrict__ TR,
    float* __restrict__ out) {
  int tid = threadIdx.x;
  if (tid < 8) {
    float su = 0.f;
    for (int c = 0; c < 64; c++) su += part[tid * 64 + c];
    float ildj = 0.f;
    const float Hsq[7] = {16384.f, 4096.f, 1024.f, 256.f, 64.f, 16.f, 4.f};
#pragma unroll
    for (int i = 0; i < 7; i++) ildj += expf(TR[i]) * Hsq[i];
    out[tid] = -0.5f * su - 0.5f * 196608.0f * 1.8378770664093453f + ildj;
  }
}

extern "C" void kernel_launch(void* const* d_in, const int* in_sizes, int n_in,
                              void* d_out, int out_size, void* d_ws, size_t ws_size,
                              hipStream_t stream) {
  (void)in_sizes; (void)n_in; (void)out_size;
  const size_t need =
      ((size_t)3 * NXEL + 2 * 98304 + 387072 + 8 + 512) * sizeof(float);
  if (ws_size < need) return;

  const float* sample = (const float*)d_in[0];
  float* ws = (float*)d_ws;
  float* Xa = ws;
  float* Xb = Xa + NXEL;
  float* XBLK = Xb + NXEL;
  float* HBUF = XBLK + 262144;
  float* TCUR = XBLK + NXEL;
  float* MT = TCUR;
  __hip_bfloat16* CWT1 = (__hip_bfloat16*)(TCUR + 12240);
  __hip_bfloat16* CWT2 = (__hip_bfloat16*)(TCUR + 20432);
  float* TNXT = TCUR + 98304;
  __hip_bfloat16* MTB = (__hip_bfloat16*)(TNXT + 98304);
  float* TR = (float*)(MTB + 774144);
  float* PART = TR + 8;
  float* out = (float*)d_out;

  const float* Mp[7];
  const float *ebp[7], *cwp[7], *cbp[7], *dwp[7], *dbp[7];
  for (int i = 0; i < 7; i++) {
    Mp[i] = (const float*)d_in[1 + 6 * i + 0];
    ebp[i] = (const float*)d_in[1 + 6 * i + 1];
    cwp[i] = (const float*)d_in[1 + 6 * i + 2];
    cbp[i] = (const float*)d_in[1 + 6 * i + 3];
    dwp[i] = (const float*)d_in[1 + 6 * i + 4];
    dbp[i] = (const float*)d_in[1 + 6 * i + 5];
  }

  prep_all_kernel<<<3271, 256, 0, stream>>>(
      Mp[0], Mp[1], Mp[2], Mp[3], Mp[4], Mp[5], Mp[6], cwp[0], cwp[1], MT, MTB,
      TR, CWT1, CWT2);

  const int Jarr[7] = {5, 5, 6, 7, 7, 8, 10};
  const int MTOFF[4] = {0, 144, 720, 3024};
  const int MTBOFF[3] = {0, 36864, 184320};
  const int PIXa[7] = {0, 0, 0, 8, 8, 4, 2};
  const int KCa[7] = {0, 0, 0, 4, 16, 32, 64};

  int C = 3;
  for (int i = 0; i < 7; i++) {
    int s = 12 << i, d = s >> 1, h = 128 >> i;
    int Cp = C;
    int Cfull = 4 * C;
    int pass = Cfull - s;
    int nvec = 8 * h * h;
    float* xs2d = (i & 1) ? Xb : Xa;
    const float* prev = (i == 0) ? sample : ((i & 1) ? Xa : Xb);

    if (s <= 96) {
      int tvs = i + 1;
      int NV = 256 >> tvs;
      int ldsB = (s * s + NV * (s + 1)) * 4;
      expm_apply_kernel<<<nvec / NV, 256, ldsB, stream>>>(
          prev, MT + MTOFF[i], ebp[i], XBLK, s, Cp, h, Jarr[i], tvs);
    } else if (i == 4) {
      expm_chain_kernel<192><<<nvec, 192, 0, stream>>>(
          prev, MTB + MTBOFF[0], ebp[i], XBLK, Cp, h, Jarr[i]);
    } else {
      expm_init_kernel<<<384, 64, 0, stream>>>(prev, ebp[i], TCUR, XBLK, s, Cp,
                                               h, nvec);
      float* ta = TCUR;
      float* tb = TNXT;
      dim3 g(s / 64, nvec);
      for (int j = 1; j <= Jarr[i]; j++) {
        if (i == 5)
          taylor_term_kernel<384><<<g, 64, 0, stream>>>(
              MTB + MTBOFF[1], ta, tb, XBLK, 1.0f / (float)j);
        else
          taylor_term_kernel<768><<<g, 64, 0, stream>>>(
              MTB + MTBOFF[2], ta, tb, XBLK, 1.0f / (float)j);
        float* tmp = ta; ta = tb; tb = tmp;
      }
    }

    if (i == 0) {
      int blocks = 8 * (h / 8) * (h / 8);
      int ldsB = 64 * (64 + 8) * 2 + (256 * 6 + 256) * 4;
      conv_dense_mfma<6, 2><<<blocks, 256, ldsB, stream>>>(
          XBLK, xs2d, CWT1, cbp[0], dwp[0], dbp[0], prev, h, s, Cfull, Cp, pass);
    } else if (i == 1) {
      int blocks = 8 * (h / 8) * (h / 8);
      int ldsB = 64 * (128 + 8) * 2 + (256 * 12 + 256) * 4;
      conv_dense_mfma<12, 4><<<blocks, 256, ldsB, stream>>>(
          XBLK, xs2d, CWT2, cbp[1], dwp[1], dbp[1], prev, h, s, Cfull, Cp, pass);
    } else if (i == 2) {
      int blocks = 8 * (h / 4) * (h / 4);
      int ldsB = (2 * 256 * (d + 1) + 16 * 257) * 4;
      conv_dense_v3<4, 4, 24><<<blocks, 256, ldsB, stream>>>(
          XBLK, xs2d, cwp[i], cbp[i], dwp[i], dbp[i], prev, h, s, Cfull, Cp, pass);
    } else {
      hipMemsetAsync(HBUF, 0, (size_t)nvec * 256 * 4, stream);
      int PIX = PIXa[i], KC = KCa[i];
      int nine_d = 9 * d;
      int chunk = (nine_d + KC - 1) / KC;
      dim3 ga(nvec / PIX, KC);
      int alds = PIX * chunk * 4;
      if (PIX == 8)
        conv_part_kernel<8><<<ga, 256, alds, stream>>>(XBLK, cwp[i], HBUF, h, d, s, chunk);
      else if (PIX == 4)
        conv_part_kernel<4><<<ga, 256, alds, stream>>>(XBLK, cwp[i], HBUF, h, d, s, chunk);
      else
        conv_part_kernel<2><<<ga, 256, alds, stream>>>(XBLK, cwp[i], HBUF, h, d, s, chunk);
      long shiftN = (long)nvec * d, passT = (long)nvec * pass;
      int dsb = (int)((shiftN + 255) / 256 + (passT + 255) / 256);
      if (dsb > 4096) dsb = 4096;
      dense_shift_kernel<<<dsb, 256, 0, stream>>>(
          XBLK, HBUF, xs2d, dwp[i], dbp[i], cbp[i], prev, d, s, Cfull, Cp, pass,
          h, nvec);
    }
    C = Cfull;
  }

  sumsq_kernel<<<512, 256, 0, stream>>>(Xa, PART);
  finalize_kernel<<<1, 256, 0, stream>>>(PART, TR, out);
}

// Round 18
// 477.641 us; speedup vs baseline: 1.0227x; 1.0211x over previous
//
#include <hip/hip_runtime.h>
#include <hip/hip_bf16.h>
#include <math.h>

// Flow log_prob. R18: conv_dense_mfma stages cwT in LDS (L1 whole, L2 in two
// halves). R17 diagnosis: occupancy 41% but still 70% stalled -- the per-nt
// B-operand global stream (1-deep prefetch ~100cy of work vs 200-400cy L2
// latency, 16x re-stream of cwT per block) dominates. Hot loop is now pure
// LDS(b64, 2-way-free stride KP+12) + MFMA + VALU dense.

#define NXEL 1572864  // 8*256*256*3

typedef __attribute__((ext_vector_type(8))) short bf16x8;
typedef __attribute__((ext_vector_type(4))) float f32x4;

__device__ inline unsigned pkbf(float a, float b) {
  union { __hip_bfloat16 h; unsigned short u; } ca, cb2;
  ca.h = __float2bfloat16(a);
  cb2.h = __float2bfloat16(b);
  return (unsigned)ca.u | ((unsigned)cb2.u << 16);
}

__device__ inline bf16x8 ld_bf16x8_8B(const __hip_bfloat16* p) {
  const uint2* q = (const uint2*)p;  // 8B-aligned LDS load
  union { uint2 u[2]; bf16x8 v; } r;
  r.u[0] = q[0];
  r.u[1] = q[1];
  return r.v;
}

// ---------- one-shot prep ----------
__global__ __launch_bounds__(256) void prep_all_kernel(
    const float* __restrict__ M1, const float* __restrict__ M2,
    const float* __restrict__ M3, const float* __restrict__ M4,
    const float* __restrict__ M5, const float* __restrict__ M6,
    const float* __restrict__ M7, const float* __restrict__ cw1,
    const float* __restrict__ cw2, float* __restrict__ MT,
    __hip_bfloat16* __restrict__ MTB, float* __restrict__ TR,
    __hip_bfloat16* __restrict__ CWT1, __hip_bfloat16* __restrict__ CWT2) {
  int bid = blockIdx.x, tid = threadIdx.x;
  if (bid < 48) {
    int idx = bid * 256 + tid;
    if (idx < 12240) {
      const int cum[5] = {0, 144, 720, 3024, 12240};
      int l = 0;
      while (idx >= cum[l + 1]) l++;
      int local = idx - cum[l];
      int s = 12 << l;
      int k = local / s, c = local - k * s;
      const float* Mp = l == 0 ? M1 : l == 1 ? M2 : l == 2 ? M3 : M4;
      MT[idx] = -Mp[c * s + k];
    }
  } else if (bid < 3072) {
    int idx = (bid - 48) * 256 + tid;
    if (idx < 774144) {
      const int cum[4] = {0, 36864, 184320, 774144};
      int l = 0;
      while (idx >= cum[l + 1]) l++;
      const float* Mp = l == 0 ? M5 : l == 1 ? M6 : M7;
      MTB[idx] = __float2bfloat16(-Mp[idx - cum[l]]);
    }
  } else if (bid < 3079) {
    __shared__ float red[256];
    int l = bid - 3072;
    const float* Mp = l == 0 ? M1 : l == 1 ? M2 : l == 2 ? M3 : l == 3 ? M4
                    : l == 4 ? M5 : l == 5 ? M6 : M7;
    int s = 12 << l;
    float su = 0.f;
    for (int i = tid; i < s; i += 256) su += Mp[(long)i * s + i];
    red[tid] = su;
    __syncthreads();
    for (int st = 128; st > 0; st >>= 1) {
      if (tid < st) red[tid] += red[tid + st];
      __syncthreads();
    }
    if (tid == 0) TR[l] = red[0];
  } else if (bid < 3143) {
    int idx = (bid - 3079) * 256 + tid;
    int n = idx >> 6, k = idx & 63;
    CWT1[idx] = __float2bfloat16(k < 54 ? cw1[k * 256 + n] : 0.f);
  } else {
    int idx = (bid - 3143) * 256 + tid;
    int n = idx >> 7, k = idx & 127;
    CWT2[idx] = __float2bfloat16(k < 108 ? cw2[k * 256 + n] : 0.f);
  }
}

// ---- levels 1-4: in-block Taylor chain, M in LDS; reads prev via s2d map ----
__global__ __launch_bounds__(256) void expm_apply_kernel(
    const float* __restrict__ prev, const float* __restrict__ Mt,
    const float* __restrict__ eb, float* __restrict__ xblk,
    int s, int Cp, int h, int J, int tvs) {
  extern __shared__ float lds[];
  float* MtS = lds;
  float* Tb = lds + s * s;
  for (int i = threadIdx.x; i < s * s; i += 256) MtS[i] = Mt[i];

  int TV = 1 << tvs;
  int v = threadIdx.x >> tvs;
  int p = threadIdx.x & (TV - 1);
  int c0 = p * 6;
  int NV = 256 >> tvs;
  int sp = s + 1;
  int vec = blockIdx.x * NV + v;
  int hw = h * h;
  int b = vec / hw, rem = vec - b * hw;
  int y = rem / h, x = rem - (rem / h) * h;
  int W2 = 2 * h;
  long rowbase = ((long)(b * W2 + 2 * y) * W2 + 2 * x) * Cp;

  float acc[6];
#pragma unroll
  for (int m = 0; m < 6; m++) {
    int c = c0 + m;
    int q = c / Cp, cp = c - q * Cp;
    float xv = prev[rowbase + (long)((q >> 1) * W2 + (q & 1)) * Cp + cp] - eb[c];
    acc[m] = xv;
    Tb[v * sp + c0 + m] = xv;
  }
  __syncthreads();

  for (int j = 1; j <= J; j++) {
    float inv = 1.0f / (float)j;
    float tn[6] = {0.f, 0.f, 0.f, 0.f, 0.f, 0.f};
    const float* Trow = Tb + v * sp;
    for (int k = 0; k < s; k++) {
      float tv = Trow[k];
      const float* mrow = MtS + k * s + c0;
#pragma unroll
      for (int m = 0; m < 6; m++) tn[m] = fmaf(mrow[m], tv, tn[m]);
    }
    __syncthreads();
#pragma unroll
    for (int m = 0; m < 6; m++) {
      float t2 = tn[m] * inv;
      acc[m] += t2;
      Tb[v * sp + c0 + m] = t2;
    }
    __syncthreads();
  }

  float* xo = xblk + (long)vec * s;
#pragma unroll
  for (int m = 0; m < 6; m++) xo[c0 + m] = acc[m];
}

// ---- level 5 (S=192): fused Taylor chain, full M row in regs (96 VGPR) ----
template <int S>
__global__ __launch_bounds__(S, 2) void expm_chain_kernel(
    const float* __restrict__ prev, const __hip_bfloat16* __restrict__ Mrow,
    const float* __restrict__ eb, float* __restrict__ xblk,
    int Cp, int h, int J) {
  constexpr int NU4 = S / 8;
  __shared__ float tbuf[2][S];
  int c = threadIdx.x;
  int vec = blockIdx.x;
  int hw = h * h, W2 = 2 * h;
  int b = vec / hw, rem = vec - b * hw;
  int y = rem / h, x = rem - (rem / h) * h;
  int q = c / Cp, cp = c - q * Cp;
  long a = ((long)(b * W2 + 2 * y + (q >> 1)) * W2 + 2 * x + (q & 1)) * Cp + cp;

  uint4 mreg[NU4];
  const uint4* rp = (const uint4*)(Mrow + (long)c * S);
#pragma unroll
  for (int k8 = 0; k8 < NU4; k8++) mreg[k8] = rp[k8];

  float v = prev[a] - eb[c];
  float acc = v;
  tbuf[0][c] = v;
  __syncthreads();

  int cur = 0;
  for (int j = 1; j <= J; j++) {
    float inv = 1.0f / (float)j;
    float sacc[4] = {0.f, 0.f, 0.f, 0.f};
    const float* t = tbuf[cur];
#pragma unroll
    for (int k8 = 0; k8 < NU4; k8++) {
      uint4 u = mreg[k8];
      const float* tt = t + (k8 << 3);
      float ss = sacc[k8 & 3];
      ss = fmaf(__uint_as_float(u.x << 16), tt[0], ss);
      ss = fmaf(__uint_as_float(u.x & 0xffff0000u), tt[1], ss);
      ss = fmaf(__uint_as_float(u.y << 16), tt[2], ss);
      ss = fmaf(__uint_as_float(u.y & 0xffff0000u), tt[3], ss);
      ss = fmaf(__uint_as_float(u.z << 16), tt[4], ss);
      ss = fmaf(__uint_as_float(u.z & 0xffff0000u), tt[5], ss);
      ss = fmaf(__uint_as_float(u.w << 16), tt[6], ss);
      ss = fmaf(__uint_as_float(u.w & 0xffff0000u), tt[7], ss);
      sacc[k8 & 3] = ss;
    }
    float tn = ((sacc[0] + sacc[1]) + (sacc[2] + sacc[3])) * inv;
    acc += tn;
    cur ^= 1;
    tbuf[cur][c] = tn;
    __syncthreads();
  }
  xblk[(long)vec * S + c] = acc;
}

// ---- levels 6-7: per-term Taylor (streaming M from L2; allocator-proof) ----
__global__ __launch_bounds__(64) void expm_init_kernel(
    const float* __restrict__ prev, const float* __restrict__ eb,
    float* __restrict__ tcur, float* __restrict__ acc, int s, int Cp, int h,
    int nvec) {
  int total = nvec * s;
  int hw = h * h, W2 = 2 * h;
  for (int idx = blockIdx.x * 64 + threadIdx.x; idx < total;
       idx += gridDim.x * 64) {
    int v = idx / s, c = idx - (idx / s) * s;
    int b = v / hw, rem = v - b * hw;
    int y = rem / h, x = rem - (rem / h) * h;
    int q = c / Cp, cp = c - q * Cp;
    long a = ((long)(b * W2 + 2 * y + (q >> 1)) * W2 + 2 * x + (q & 1)) * Cp + cp;
    float xv = prev[a] - eb[c];
    tcur[idx] = xv;
    acc[idx] = xv;
  }
}

template <int S>
__global__ __launch_bounds__(64) void taylor_term_kernel(
    const __hip_bfloat16* __restrict__ Mrow, const float* __restrict__ t_old,
    float* __restrict__ t_new, float* __restrict__ acc, float inv_j) {
  __shared__ float tv[S];
  int tid = threadIdx.x;
  int v = blockIdx.y;
  int c = blockIdx.x * 64 + tid;
  const float4* t4 = (const float4*)(t_old + (long)v * S);
  float4* l4 = (float4*)tv;
  for (int i = tid; i < S / 4; i += 64) l4[i] = t4[i];
  __syncthreads();

  const uint4* rp = (const uint4*)(Mrow + (long)c * S);
  float sacc[4] = {0.f, 0.f, 0.f, 0.f};
#pragma unroll
  for (int k8 = 0; k8 < S / 8; k8++) {
    uint4 u = rp[k8];
    const float* tt = tv + (k8 << 3);
    float ss = sacc[k8 & 3];
    ss = fmaf(__uint_as_float(u.x << 16), tt[0], ss);
    ss = fmaf(__uint_as_float(u.x & 0xffff0000u), tt[1], ss);
    ss = fmaf(__uint_as_float(u.y << 16), tt[2], ss);
    ss = fmaf(__uint_as_float(u.y & 0xffff0000u), tt[3], ss);
    ss = fmaf(__uint_as_float(u.z << 16), tt[4], ss);
    ss = fmaf(__uint_as_float(u.z & 0xffff0000u), tt[5], ss);
    ss = fmaf(__uint_as_float(u.w << 16), tt[6], ss);
    ss = fmaf(__uint_as_float(u.w & 0xffff0000u), tt[7], ss);
    sacc[k8 & 3] = ss;
  }
  float tn = ((sacc[0] + sacc[1]) + (sacc[2] + sacc[3])) * inv_j;
  long o = (long)v * S + c;
  t_new[o] = tn;
  acc[o] += tn;
}

// ---- levels 1-2: MFMA conv3x3(D->256) with LDS-resident B + VALU dense ----
// NSPLIT: cwT staged in NSPLIT chunks of 256/NSPLIT output channels.
template <int D, int KSTEPS, int NSPLIT>
__global__ __launch_bounds__(256) void conv_dense_mfma(
    const float* __restrict__ xblk, float* __restrict__ xout,
    const __hip_bfloat16* __restrict__ cwT, const float* __restrict__ cb,
    const float* __restrict__ dw, const float* __restrict__ db,
    const float* __restrict__ prev, int h, int s, int Cfull, int Cp, int pass) {
  constexpr int K9 = 9 * D;
  constexpr int KP = KSTEPS * 32;
  constexpr int CROWS = 256 / NSPLIT;
  constexpr int CSTR = KP + 12;  // 2-mod-4-word stride: 2-way (free), 8B align
  extern __shared__ __hip_bfloat16 uls[];
  __hip_bfloat16* A = uls;                         // [64][KP] (unpadded)
  __hip_bfloat16* cwS = uls + 64 * KP;             // [CROWS][CSTR]
  float* dwS = (float*)(cwS + CROWS * CSTR);       // [256][D]
  float* cbS = dwS + 256 * D;                      // [256]

  int w = h;
  int tilesX = w >> 3;
  int bt = blockIdx.x;
  int tx = bt % tilesX; int t1 = bt / tilesX;
  int ty = t1 % tilesX; int b = t1 / tilesX;
  int y0 = ty * 8, x0 = tx * 8;
  int tid = threadIdx.x;

  for (int idx = tid; idx < 256 * D; idx += 256) dwS[idx] = dw[idx];
  cbS[tid] = cb[tid];

#pragma unroll
  for (int it = 0; it < 3; ++it) {
    int idx = it * 256 + tid;
    if (idx < 576) {
      int m = idx / 9, t = idx - m * 9;
      int ky = t / 3, kx = t - ky * 3;
      int pr = m >> 3, pc = m & 7;
      int iy = y0 + pr + ky - 1, ix = x0 + pc + kx - 1;
      unsigned* dst = (unsigned*)&A[m * KP + t * D];
      if (iy >= 0 && iy < h && ix >= 0 && ix < w) {
        const float* src = &xblk[((long)((b * h + iy) * w + ix)) * s];
        if constexpr (D == 6) {
          float4 p0 = *(const float4*)src;
          float2 p1 = *(const float2*)(src + 4);
          dst[0] = pkbf(p0.x, p0.y);
          dst[1] = pkbf(p0.z, p0.w);
          dst[2] = pkbf(p1.x, p1.y);
        } else {
          float4 p0 = ((const float4*)src)[0];
          float4 p1 = ((const float4*)src)[1];
          float4 p2 = ((const float4*)src)[2];
          dst[0] = pkbf(p0.x, p0.y);
          dst[1] = pkbf(p0.z, p0.w);
          dst[2] = pkbf(p1.x, p1.y);
          dst[3] = pkbf(p1.z, p1.w);
          dst[4] = pkbf(p2.x, p2.y);
          dst[5] = pkbf(p2.z, p2.w);
        }
      } else {
#pragma unroll
        for (int j = 0; j < D / 2; j++) dst[j] = 0u;
      }
    }
  }
  constexpr int PADU = (KP - K9) / 2;
  for (int idx = tid; idx < 64 * PADU; idx += 256) {
    int m = idx / PADU, j = idx - m * PADU;
    ((unsigned*)&A[m * KP + K9])[j] = 0u;
  }
  __syncthreads();

  int wid = tid >> 6, lane = tid & 63;
  int ln = lane & 15, hi = lane >> 4;

  bf16x8 af[KSTEPS];
#pragma unroll
  for (int ks = 0; ks < KSTEPS; ks++)
    af[ks] = *(const bf16x8*)&A[(wid * 16 + ln) * KP + ks * 32 + hi * 8];

  float part[4][D];
#pragma unroll
  for (int r = 0; r < 4; r++)
#pragma unroll
    for (int c = 0; c < D; c++) part[r][c] = 0.f;

#pragma unroll 1
  for (int half = 0; half < NSPLIT; half++) {
    // stage cwT rows [half*CROWS, (half+1)*CROWS) into LDS
    for (int idx = tid; idx < CROWS * (KP / 8); idx += 256) {
      int rr = idx / (KP / 8), pos = (idx - rr * (KP / 8)) * 8;
      uint4 u = *(const uint4*)&cwT[(long)(half * CROWS + rr) * KP + pos];
      uint2* dst = (uint2*)&cwS[rr * CSTR + pos];
      dst[0] = make_uint2(u.x, u.y);
      dst[1] = make_uint2(u.z, u.w);
    }
    __syncthreads();

#pragma unroll 1
    for (int ntl = 0; ntl < 16 / NSPLIT; ntl++) {
      int nt = half * (16 / NSPLIT) + ntl;
      bf16x8 bq[KSTEPS];
#pragma unroll
      for (int ks = 0; ks < KSTEPS; ks++)
        bq[ks] = ld_bf16x8_8B(&cwS[(ntl * 16 + ln) * CSTR + ks * 32 + hi * 8]);
      f32x4 acc = {0.f, 0.f, 0.f, 0.f};
#pragma unroll
      for (int ks = 0; ks < KSTEPS; ks++)
        acc = __builtin_amdgcn_mfma_f32_16x16x32_bf16(af[ks], bq[ks], acc, 0, 0, 0);
      int k = nt * 16 + ln;
      float cbv = cbS[k];
      const float* dr = dwS + k * D;
#pragma unroll
      for (int r = 0; r < 4; r++) {
        float hv = fmaxf(acc[r] + cbv, 0.f);
#pragma unroll
        for (int c = 0; c < D; c++) part[r][c] = fmaf(hv, dr[c], part[r][c]);
      }
    }
    __syncthreads();  // readers done before next restage (no-op for NSPLIT=1)
  }

  // butterfly reduce over the 16 ln lanes (same hi group -> same m rows)
#pragma unroll
  for (int msk = 1; msk <= 8; msk <<= 1)
#pragma unroll
    for (int r = 0; r < 4; r++)
#pragma unroll
      for (int c = 0; c < D; c++)
        part[r][c] += __shfl_xor(part[r][c], msk, 64);

  if (ln == 0) {
#pragma unroll
    for (int r = 0; r < 4; r++) {
      int m = wid * 16 + hi * 4 + r;
      int pr = m >> 3, pc = m & 7;
      long pix = (long)((b * h + y0 + pr) * w + (x0 + pc));
#pragma unroll
      for (int c = 0; c < D; c++)
        xout[pix * Cfull + D + c] = xblk[pix * s + D + c] - (part[r][c] + db[c]);
    }
  }

  // x0 copy (channels [0,D))
  for (int idx = tid; idx < 64 * D; idx += 256) {
    int m = idx / D, c = idx - (idx / D) * D;
    int pr = m >> 3, pc = m & 7;
    long pix = (long)((b * h + y0 + pr) * w + (x0 + pc));
    xout[pix * Cfull + c] = xblk[pix * s + c];
  }

  // passthrough [s, Cfull)
  if (pass > 0) {
    int W2 = 2 * h;
    int nq = pass / Cp;
    int q0 = s / Cp;
    int tasks = 64 * nq;
    for (int idx = tid; idx < tasks; idx += 256) {
      int m = idx / nq, qi = idx - (idx / nq) * nq;
      int q = q0 + qi;
      int pr = m >> 3, pc = m & 7;
      int yy = y0 + pr, xx = x0 + pc;
      const float4* src = (const float4*)
          &prev[((long)(b * W2 + 2 * yy + (q >> 1)) * W2 + 2 * xx + (q & 1)) * Cp];
      float4* dst = (float4*)&xout[((long)((b * h + yy) * w + xx)) * Cfull + q * Cp];
      for (int j = 0; j < Cp / 4; j++) dst[j] = src[j];
    }
  }
}

// ---- level 3: fused conv+dense v3 (VALU) ----
template <int TH, int TW, int D>
__global__ __launch_bounds__(256) void conv_dense_v3(
    const float* __restrict__ xblk, float* __restrict__ xout,
    const float* __restrict__ cw, const float* __restrict__ cb,
    const float* __restrict__ dw, const float* __restrict__ db,
    const float* __restrict__ prev, int h, int s, int Cfull, int Cp, int pass) {
  constexpr int P = TH * TW;
  constexpr int PW = 8;
  constexpr int DP = D + 1;
  extern __shared__ float lds[];
  float* dwS = lds;
  float* hbufS = dwS + 256 * DP;
  float* scratch = hbufS + P * 257;
  float* patchS = scratch;

  int w = h;
  int tilesX = w / TW, tilesY = h / TH;
  int bt = blockIdx.x;
  int tx = bt % tilesX; int t1 = bt / tilesX;
  int ty = t1 % tilesY; int b = t1 / tilesY;
  int y0 = ty * TH, x0 = tx * TW;
  int tid = threadIdx.x;

  for (int idx = tid; idx < 256 * D; idx += 256) {
    int k = idx / D, c = idx % D;
    dwS[k * DP + c] = dw[idx];
  }

  constexpr int PATCHN = D * (TH + 2) * (TW + 2);
  for (int idx = tid; idx < PATCHN; idx += 256) {
    int ci = idx % D; int rest = idx / D;
    int px = rest % (TW + 2); int py = rest / (TW + 2);
    int iy = y0 + py - 1, ix = x0 + px - 1;
    float v = 0.f;
    if (iy >= 0 && iy < h && ix >= 0 && ix < w)
      v = xblk[((long)((b * h + iy) * w + ix)) * s + ci];
    patchS[(ci * (TH + 2) + py) * PW + px] = v;
  }
  __syncthreads();

  float acc[P];
  float cbk = cb[tid];
#pragma unroll
  for (int p = 0; p < P; p++) acc[p] = cbk;

  float wv[9];
#pragma unroll
  for (int t = 0; t < 9; t++) wv[t] = cw[(long)(t * D) * 256 + tid];

#pragma unroll 1
  for (int ci = 0; ci < D; ci++) {
    float wvn[9];
    if (ci + 1 < D) {
#pragma unroll
      for (int t = 0; t < 9; t++) wvn[t] = cw[(long)(t * D + ci + 1) * 256 + tid];
    }
    float r[TH + 2][6];
#pragma unroll
    for (int py = 0; py < TH + 2; py++) {
      const float* rp = &patchS[(ci * (TH + 2) + py) * PW];
#pragma unroll
      for (int u = 0; u < 6; u++) r[py][u] = rp[u];
    }
#pragma unroll
    for (int ky = 0; ky < 3; ky++)
#pragma unroll
      for (int kx = 0; kx < 3; kx++)
#pragma unroll
        for (int pr = 0; pr < TH; pr++)
#pragma unroll
          for (int pc = 0; pc < TW; pc++)
            acc[pr * TW + pc] =
                fmaf(r[pr + ky][pc + kx], wv[ky * 3 + kx], acc[pr * TW + pc]);
#pragma unroll
    for (int t = 0; t < 9; t++) wv[t] = wvn[t];
  }
#pragma unroll
  for (int p = 0; p < P; p++) hbufS[p * 257 + tid] = fmaxf(acc[p], 0.f);
  __syncthreads();

  {
    int p = tid & 15, kc = tid >> 4;
    float part[D];
#pragma unroll
    for (int c = 0; c < D; c++) part[c] = 0.f;
    const float* hrow = hbufS + p * 257 + kc * 16;
#pragma unroll
    for (int k = 0; k < 16; k++) {
      float hv = hrow[k];
      const float* dr = dwS + (kc * 16 + k) * DP;
#pragma unroll
      for (int c = 0; c < D; c++) part[c] = fmaf(hv, dr[c], part[c]);
    }
    __syncthreads();
    float* partial = scratch;
#pragma unroll
    for (int c = 0; c < D; c++) partial[(kc * 16 + p) * DP + c] = part[c];
  }
  __syncthreads();

  for (int idx = tid; idx < P * D; idx += 256) {
    int p = idx / D, c = idx % D;
    float sh = db[c];
    const float* pp = scratch + p * DP + c;
#pragma unroll
    for (int kc = 0; kc < 16; kc++) sh += pp[kc * 16 * DP];
    int pr = p / TW, pc = p % TW;
    long pix = (long)((b * h + y0 + pr) * w + (x0 + pc));
    float x0v = xblk[pix * s + c];
    float x1v = xblk[pix * s + D + c];
    xout[pix * Cfull + c] = x0v;
    xout[pix * Cfull + D + c] = x1v - sh;
  }

  if (pass > 0) {
    int W2 = 2 * h;
    for (int idx = tid; idx < P * pass; idx += 256) {
      int pp = idx / pass, c = 2 * D + idx - (idx / pass) * pass;
      int pr = pp / TW, pc = pp - (pp / TW) * TW;
      int yy = y0 + pr, xx = x0 + pc;
      int q = c / Cp, cp = c - q * Cp;
      long a = ((long)(b * W2 + 2 * yy + (q >> 1)) * W2 + 2 * xx + (q & 1)) * Cp + cp;
      xout[((long)((b * h + yy) * w + xx)) * Cfull + c] = prev[a];
    }
  }
}

// ---- levels 4-7: K-split conv (atomic on zeroed hbuf) + dense + passthrough
template <int PIX>
__global__ __launch_bounds__(256) void conv_part_kernel(
    const float* __restrict__ xblk, const float* __restrict__ cw,
    float* __restrict__ hbuf, int h, int d, int s, int chunk) {
  extern __shared__ float pt[];
  int w = h;
  int nine_d = 9 * d;
  int j0 = blockIdx.y * chunk;
  int j1 = min(j0 + chunk, nine_d);
  int clen = j1 - j0;
  int pg = blockIdx.x;
  int tid = threadIdx.x;

  for (int idx = tid; idx < PIX * clen; idx += 256) {
    int q = idx / clen, jj = idx % clen;
    int j = j0 + jj;
    int t = j / d, ci = j - t * d;
    int ky = t / 3, kx = t % 3;
    int p = pg * PIX + q;
    int b = p / (h * w); int rem = p - b * h * w;
    int y = rem / w, x = rem - y * w;
    int iy = y + ky - 1, ix = x + kx - 1;
    float v = 0.f;
    if (iy >= 0 && iy < h && ix >= 0 && ix < w)
      v = xblk[((long)((b * h + iy) * w + ix)) * s + ci];
    pt[idx] = v;
  }
  __syncthreads();

  float acc[PIX];
#pragma unroll
  for (int q = 0; q < PIX; q++) acc[q] = 0.f;
  const float* cwp = cw + (long)j0 * 256 + tid;
#pragma unroll 4
  for (int jj = 0; jj < clen; jj++) {
    float cwv = cwp[(long)jj * 256];
#pragma unroll
    for (int q = 0; q < PIX; q++) acc[q] = fmaf(pt[q * clen + jj], cwv, acc[q]);
  }
#pragma unroll
  for (int q = 0; q < PIX; q++)
    atomicAdd(&hbuf[((long)(pg * PIX + q)) * 256 + tid], acc[q]);
}

__global__ __launch_bounds__(256) void dense_shift_kernel(
    const float* __restrict__ xblk, const float* __restrict__ hbuf,
    float* __restrict__ xout, const float* __restrict__ dw,
    const float* __restrict__ db, const float* __restrict__ cb,
    const float* __restrict__ prev, int d, int s, int Cfull, int Cp, int pass,
    int h, int nvec) {
  __shared__ float cbS[256];
  cbS[threadIdx.x] = cb[threadIdx.x];
  __syncthreads();
  int shiftN = nvec * d;
  for (int gid = blockIdx.x * 256 + threadIdx.x; gid < shiftN;
       gid += gridDim.x * 256) {
    int p = gid / d, c = gid - (gid / d) * d;
    float sum = db[c];
    const float* hrow = hbuf + (long)p * 256;
#pragma unroll 4
    for (int k = 0; k < 256; k++)
      sum = fmaf(fmaxf(hrow[k] + cbS[k], 0.f), dw[(long)k * d + c], sum);
    long pix = p;
    float x0v = xblk[pix * s + c];
    float x1v = xblk[pix * s + d + c];
    xout[pix * Cfull + c] = x0v;
    xout[pix * Cfull + d + c] = x1v - sum;
  }
  int hw = h * h, W2 = 2 * h;
  long passT = (long)nvec * pass;
  for (long e = blockIdx.x * 256 + threadIdx.x; e < passT;
       e += (long)gridDim.x * 256) {
    int p = (int)(e / pass);
    int c = s + (int)(e - (long)p * pass);
    int b = p / hw, rem = p - b * hw;
    int y = rem / h, x = rem - (rem / h) * h;
    int q = c / Cp, cp = c - q * Cp;
    long a = ((long)(b * W2 + 2 * y + (q >> 1)) * W2 + 2 * x + (q & 1)) * Cp + cp;
    xout[(long)p * Cfull + c] = prev[a];
  }
}

__global__ __launch_bounds__(256) void sumsq_kernel(const float* __restrict__ x,
                                                    float* __restrict__ part) {
  __shared__ float red[256];
  int b = blockIdx.x >> 6, ch = blockIdx.x & 63;
  const float* p = x + (long)b * 196608 + ch * 3072;
  float su = 0.f;
  for (int i = threadIdx.x; i < 3072; i += 256) {
    float v = p[i];
    su = fmaf(v, v, su);
  }
  red[threadIdx.x] = su;
  __syncthreads();
  for (int st = 128; st > 0; st >>= 1) {
    if (threadIdx.x < st) red[threadIdx.x] += red[threadIdx.x + st];
    __syncthreads();
  }
  if (threadIdx.x == 0) part[blockIdx.x] = red[0];
}

__global__ __launch_bounds__(256) void finalize_kernel(
    const float* __restrict__ part, const float* __restrict__ TR,
    float* __restrict__ out) {
  int tid = threadIdx.x;
  if (tid < 8) {
    float su = 0.f;
    for (int c = 0; c < 64; c++) su += part[tid * 64 + c];
    float ildj = 0.f;
    const float Hsq[7] = {16384.f, 4096.f, 1024.f, 256.f, 64.f, 16.f, 4.f};
#pragma unroll
    for (int i = 0; i < 7; i++) ildj += expf(TR[i]) * Hsq[i];
    out[tid] = -0.5f * su - 0.5f * 196608.0f * 1.8378770664093453f + ildj;
  }
}

extern "C" void kernel_launch(void* const* d_in, const int* in_sizes, int n_in,
                              void* d_out, int out_size, void* d_ws, size_t ws_size,
                              hipStream_t stream) {
  (void)in_sizes; (void)n_in; (void)out_size;
  const size_t need =
      ((size_t)3 * NXEL + 2 * 98304 + 387072 + 8 + 512) * sizeof(float);
  if (ws_size < need) return;

  const float* sample = (const float*)d_in[0];
  float* ws = (float*)d_ws;
  float* Xa = ws;
  float* Xb = Xa + NXEL;
  float* XBLK = Xb + NXEL;
  float* HBUF = XBLK + 262144;
  float* TCUR = XBLK + NXEL;
  float* MT = TCUR;
  __hip_bfloat16* CWT1 = (__hip_bfloat16*)(TCUR + 12240);
  __hip_bfloat16* CWT2 = (__hip_bfloat16*)(TCUR + 20432);
  float* TNXT = TCUR + 98304;
  __hip_bfloat16* MTB = (__hip_bfloat16*)(TNXT + 98304);
  float* TR = (float*)(MTB + 774144);
  float* PART = TR + 8;
  float* out = (float*)d_out;

  const float* Mp[7];
  const float *ebp[7], *cwp[7], *cbp[7], *dwp[7], *dbp[7];
  for (int i = 0; i < 7; i++) {
    Mp[i] = (const float*)d_in[1 + 6 * i + 0];
    ebp[i] = (const float*)d_in[1 + 6 * i + 1];
    cwp[i] = (const float*)d_in[1 + 6 * i + 2];
    cbp[i] = (const float*)d_in[1 + 6 * i + 3];
    dwp[i] = (const float*)d_in[1 + 6 * i + 4];
    dbp[i] = (const float*)d_in[1 + 6 * i + 5];
  }

  prep_all_kernel<<<3271, 256, 0, stream>>>(
      Mp[0], Mp[1], Mp[2], Mp[3], Mp[4], Mp[5], Mp[6], cwp[0], cwp[1], MT, MTB,
      TR, CWT1, CWT2);

  const int Jarr[7] = {5, 5, 6, 7, 7, 8, 10};
  const int MTOFF[4] = {0, 144, 720, 3024};
  const int MTBOFF[3] = {0, 36864, 184320};
  const int PIXa[7] = {0, 0, 0, 8, 8, 4, 2};
  const int KCa[7] = {0, 0, 0, 4, 16, 32, 64};

  int C = 3;
  for (int i = 0; i < 7; i++) {
    int s = 12 << i, d = s >> 1, h = 128 >> i;
    int Cp = C;
    int Cfull = 4 * C;
    int pass = Cfull - s;
    int nvec = 8 * h * h;
    float* xs2d = (i & 1) ? Xb : Xa;
    const float* prev = (i == 0) ? sample : ((i & 1) ? Xa : Xb);

    if (s <= 96) {
      int tvs = i + 1;
      int NV = 256 >> tvs;
      int ldsB = (s * s + NV * (s + 1)) * 4;
      expm_apply_kernel<<<nvec / NV, 256, ldsB, stream>>>(
          prev, MT + MTOFF[i], ebp[i], XBLK, s, Cp, h, Jarr[i], tvs);
    } else if (i == 4) {
      expm_chain_kernel<192><<<nvec, 192, 0, stream>>>(
          prev, MTB + MTBOFF[0], ebp[i], XBLK, Cp, h, Jarr[i]);
    } else {
      expm_init_kernel<<<384, 64, 0, stream>>>(prev, ebp[i], TCUR, XBLK, s, Cp,
                                               h, nvec);
      float* ta = TCUR;
      float* tb = TNXT;
      dim3 g(s / 64, nvec);
      for (int j = 1; j <= Jarr[i]; j++) {
        if (i == 5)
          taylor_term_kernel<384><<<g, 64, 0, stream>>>(
              MTB + MTBOFF[1], ta, tb, XBLK, 1.0f / (float)j);
        else
          taylor_term_kernel<768><<<g, 64, 0, stream>>>(
              MTB + MTBOFF[2], ta, tb, XBLK, 1.0f / (float)j);
        float* tmp = ta; ta = tb; tb = tmp;
      }
    }

    if (i == 0) {
      int blocks = 8 * (h / 8) * (h / 8);
      // A 64*64*2 + cwS 256*76*2 + dwS 256*6*4 + cb 1024 = 54272 B
      int ldsB = 64 * 64 * 2 + 256 * 76 * 2 + 256 * 6 * 4 + 1024;
      conv_dense_mfma<6, 2, 1><<<blocks, 256, ldsB, stream>>>(
          XBLK, xs2d, CWT1, cbp[0], dwp[0], dbp[0], prev, h, s, Cfull, Cp, pass);
    } else if (i == 1) {
      int blocks = 8 * (h / 8) * (h / 8);
      // A 64*128*2 + cwS 128*140*2 + dwS 256*12*4 + cb 1024 = 65536 B
      int ldsB = 64 * 128 * 2 + 128 * 140 * 2 + 256 * 12 * 4 + 1024;
      conv_dense_mfma<12, 4, 2><<<blocks, 256, ldsB, stream>>>(
          XBLK, xs2d, CWT2, cbp[1], dwp[1], dbp[1], prev, h, s, Cfull, Cp, pass);
    } else if (i == 2) {
      int blocks = 8 * (h / 4) * (h / 4);
      int ldsB = (2 * 256 * (d + 1) + 16 * 257) * 4;
      conv_dense_v3<4, 4, 24><<<blocks, 256, ldsB, stream>>>(
          XBLK, xs2d, cwp[i], cbp[i], dwp[i], dbp[i], prev, h, s, Cfull, Cp, pass);
    } else {
      hipMemsetAsync(HBUF, 0, (size_t)nvec * 256 * 4, stream);
      int PIX = PIXa[i], KC = KCa[i];
      int nine_d = 9 * d;
      int chunk = (nine_d + KC - 1) / KC;
      dim3 ga(nvec / PIX, KC);
      int alds = PIX * chunk * 4;
      if (PIX == 8)
        conv_part_kernel<8><<<ga, 256, alds, stream>>>(XBLK, cwp[i], HBUF, h, d, s, chunk);
      else if (PIX == 4)
        conv_part_kernel<4><<<ga, 256, alds, stream>>>(XBLK, cwp[i], HBUF, h, d, s, chunk);
      else
        conv_part_kernel<2><<<ga, 256, alds, stream>>>(XBLK, cwp[i], HBUF, h, d, s, chunk);
      long shiftN = (long)nvec * d, passT = (long)nvec * pass;
      int dsb = (int)((shiftN + 255) / 256 + (passT + 255) / 256);
      if (dsb > 4096) dsb = 4096;
      dense_shift_kernel<<<dsb, 256, 0, stream>>>(
          XBLK, HBUF, xs2d, dwp[i], dbp[i], cbp[i], prev, d, s, Cfull, Cp, pass,
          h, nvec);
    }
    C = Cfull;
  }

  sumsq_kernel<<<512, 256, 0, stream>>>(Xa, PART);
  finalize_kernel<<<1, 256, 0, stream>>>(PART, TR, out);
}